// Round 4
// baseline (423.145 us; speedup 1.0000x reference)
//
#include <hip/hip_runtime.h>
#include <math.h>

// B=4, T=2048, C=1024, H=16, N=64, Q=256, nc=8, BT=8192
#define BB 4
#define TT 2048
#define CC 1024
#define HH 16
#define NN 64
#define QQ 256
#define NCH 8
#define BT 8192

typedef unsigned short u16;
typedef __attribute__((ext_vector_type(8))) short bf16x8;
typedef __attribute__((ext_vector_type(4))) short bf16x4;
typedef __attribute__((ext_vector_type(4))) float f32x4;
typedef __attribute__((ext_vector_type(4))) u16 u16x4;

// f32 -> bf16 bits, round-to-nearest-even
__device__ inline u16 f2b(float x) {
  union { float f; unsigned u; } v;
  v.f = x;
  unsigned r = v.u + 0x7FFFu + ((v.u >> 16) & 1u);
  return (u16)(r >> 16);
}
__device__ inline float b2f(u16 u) {
  union { unsigned u; float f; } v;
  v.u = ((unsigned)u) << 16;
  return v.f;
}
// 16B fragment from padded LDS row via two 8B loads (conflict-friendly)
__device__ inline bf16x8 ldfrag(const u16* p) {
  bf16x4 lo = *(const bf16x4*)p;
  bf16x4 hi = *(const bf16x4*)(p + 4);
  return __builtin_shufflevector(lo, hi, 0, 1, 2, 3, 4, 5, 6, 7);
}
// stage 64x64 bf16 tile (global pitch `pitch` u16) into LDS stride-72
__device__ inline void stage_tile(const u16* __restrict__ g, size_t base,
                                  int pitch, int tid, u16* __restrict__ lds) {
#pragma unroll
  for (int it = 0; it < 2; it++) {
    int cidx = tid + it * 256;  // 0..511
    int r = cidx >> 3, c8 = (cidx & 7) * 8;
    bf16x8 v = *(const bf16x8*)(g + base + (size_t)r * pitch + c8);
    *(bf16x4*)(lds + r * 72 + c8) = __builtin_shufflevector(v, v, 0, 1, 2, 3);
    *(bf16x4*)(lds + r * 72 + c8 + 4) = __builtin_shufflevector(v, v, 4, 5, 6, 7);
  }
}

// ---------------------------------------------------------------------------
// 1. time-shift mix: xx f32, xxx -> bf16
// ---------------------------------------------------------------------------
__global__ __launch_bounds__(256) void mix_kernel(const float* __restrict__ x,
                                                  const float* __restrict__ tmx,
                                                  float* __restrict__ xx,
                                                  u16* __restrict__ xxxb) {
  size_t e = ((size_t)blockIdx.x * 256 + threadIdx.x) * 4;
  int c = (int)(e & 1023);
  size_t row = e >> 10;
  int t = (int)(row & 2047);
  float4 xv = *(const float4*)(x + e);
  float4 pv = make_float4(0.f, 0.f, 0.f, 0.f);
  if (t > 0) pv = *(const float4*)(x + e - 1024);
  float4 d = make_float4(pv.x - xv.x, pv.y - xv.y, pv.z - xv.z, pv.w - xv.w);
  *(float4*)(xx + e) = d;
  u16x4 o;
  o.x = f2b(xv.x + d.x * tmx[c + 0]);
  o.y = f2b(xv.y + d.y * tmx[c + 1]);
  o.z = f2b(xv.z + d.z * tmx[c + 2]);
  o.w = f2b(xv.w + d.w * tmx[c + 3]);
  *(u16x4*)(xxxb + e) = o;
}

// ---------------------------------------------------------------------------
// weight f32[k][n] (1024x1024) -> bf16 transposed Wt[n][k]
// ---------------------------------------------------------------------------
__global__ __launch_bounds__(256) void cvt_wT(const float* __restrict__ W0,
                                              const float* __restrict__ W1,
                                              const float* __restrict__ W2,
                                              const float* __restrict__ W3,
                                              u16* __restrict__ O0,
                                              u16* __restrict__ O1,
                                              u16* __restrict__ O2,
                                              u16* __restrict__ O3) {
  const float* W;
  u16* O;
  switch (blockIdx.z) {
    case 0: W = W0; O = O0; break;
    case 1: W = W1; O = O1; break;
    case 2: W = W2; O = O2; break;
    default: W = W3; O = O3; break;
  }
  __shared__ float t[64][65];
  int bx = blockIdx.x * 64;
  int by = blockIdx.y * 64;
#pragma unroll
  for (int it = 0; it < 16; it++) {
    int idx = it * 256 + threadIdx.x;
    int r = idx >> 6, c = idx & 63;
    t[r][c] = W[(size_t)(by + r) * 1024 + bx + c];
  }
  __syncthreads();
#pragma unroll
  for (int it = 0; it < 16; it++) {
    int idx = it * 256 + threadIdx.x;
    int n = idx >> 6, k = idx & 63;
    O[(size_t)(bx + n) * 1024 + by + k] = f2b(t[k][n]);
  }
}

// ---------------------------------------------------------------------------
// generic transpose+cvt: in f32 [R][C] -> out bf16 [C][R]  (R,C mult of 64)
// ---------------------------------------------------------------------------
__global__ __launch_bounds__(256) void cvt_T(const float* __restrict__ in,
                                             u16* __restrict__ out, int R, int C) {
  __shared__ float t[64][65];
  int c0 = blockIdx.x * 64, r0 = blockIdx.y * 64;
#pragma unroll
  for (int it = 0; it < 16; it++) {
    int idx = it * 256 + threadIdx.x;
    int r = idx >> 6, c = idx & 63;
    t[r][c] = in[(size_t)(r0 + r) * C + c0 + c];
  }
  __syncthreads();
#pragma unroll
  for (int it = 0; it < 16; it++) {
    int idx = it * 256 + threadIdx.x;
    int c = idx >> 6, r = idx & 63;
    out[(size_t)(c0 + c) * R + r0 + r] = f2b(t[r][c]);
  }
}

// ---------------------------------------------------------------------------
// bf16 MFMA GEMM (m97): A[M][K], Bt[N][K]; out f32 Cf and/or bf16 Cb (opt tanh)
// (still used for the skinny maa GEMM, N=128)
// ---------------------------------------------------------------------------
template <bool TANH>
__global__ __launch_bounds__(256) void gemm_bt_mfma(const u16* __restrict__ A,
                                                    const u16* __restrict__ Bt,
                                                    float* __restrict__ Cf,
                                                    u16* __restrict__ Cb,
                                                    int M, int N, int K) {
  __shared__ u16 As[128 * 32];
  __shared__ u16 Bs[128 * 32];
  const int tid = threadIdx.x;
  const int lane = tid & 63;
  const int row0 = blockIdx.y * 128;
  const int col0 = blockIdx.x * 128;
  const int wave = tid >> 6;
  const int wr = (wave >> 1) * 64;
  const int wc = (wave & 1) * 64;
  const int fr = lane & 15;
  const int fq = lane >> 4;

  f32x4 acc[4][4];
#pragma unroll
  for (int i = 0; i < 4; i++)
#pragma unroll
    for (int j = 0; j < 4; j++) acc[i][j] = (f32x4){0.f, 0.f, 0.f, 0.f};

  const int i0 = tid, i1 = tid + 256;
  const int ra0 = i0 >> 2, ca0 = (i0 & 3) * 8;
  const int ra1 = i1 >> 2, ca1 = (i1 & 3) * 8;

  for (int k0 = 0; k0 < K; k0 += 32) {
    __builtin_amdgcn_global_load_lds(
        (const __attribute__((address_space(1))) void*)(A + (size_t)(row0 + ra0) * K + k0 + ca0),
        (__attribute__((address_space(3))) void*)(As + i0 * 8), 16, 0, 0);
    __builtin_amdgcn_global_load_lds(
        (const __attribute__((address_space(1))) void*)(A + (size_t)(row0 + ra1) * K + k0 + ca1),
        (__attribute__((address_space(3))) void*)(As + i1 * 8), 16, 0, 0);
    __builtin_amdgcn_global_load_lds(
        (const __attribute__((address_space(1))) void*)(Bt + (size_t)(col0 + ra0) * K + k0 + ca0),
        (__attribute__((address_space(3))) void*)(Bs + i0 * 8), 16, 0, 0);
    __builtin_amdgcn_global_load_lds(
        (const __attribute__((address_space(1))) void*)(Bt + (size_t)(col0 + ra1) * K + k0 + ca1),
        (__attribute__((address_space(3))) void*)(Bs + i1 * 8), 16, 0, 0);
    __syncthreads();

    bf16x8 af[4], bf[4];
#pragma unroll
    for (int i = 0; i < 4; i++)
      af[i] = *(const bf16x8*)(As + ((wr + i * 16 + fr) * 32 + fq * 8));
#pragma unroll
    for (int j = 0; j < 4; j++)
      bf[j] = *(const bf16x8*)(Bs + ((wc + j * 16 + fr) * 32 + fq * 8));
#pragma unroll
    for (int i = 0; i < 4; i++)
#pragma unroll
      for (int j = 0; j < 4; j++)
        acc[i][j] = __builtin_amdgcn_mfma_f32_16x16x32_bf16(af[i], bf[j], acc[i][j], 0, 0, 0);
    __syncthreads();
  }
#pragma unroll
  for (int i = 0; i < 4; i++) {
    int grow = row0 + wr + i * 16 + fq * 4;
#pragma unroll
    for (int j = 0; j < 4; j++) {
      int gcol = col0 + wc + j * 16 + fr;
#pragma unroll
      for (int r = 0; r < 4; r++) {
        float vv = acc[i][j][r];
        if (TANH) vv = tanhf(vv);
        if (Cf) Cf[(size_t)(grow + r) * N + gcol] = vv;
        if (Cb) Cb[(size_t)(grow + r) * N + gcol] = f2b(vv);
      }
    }
  }
}

// ---------------------------------------------------------------------------
// Deep-pipelined bf16 GEMM v4 (m201-template port): M=8192, N=1024, K=1024.
// BM=BN=256, BK=64, 512 threads = 8 waves (2M x 4N), per-wave 128x64
// -> 24 ds_read_b128 per 64 MFMA per wave (0.375, the m201 ratio), 2 waves/SIMD.
// 2 LDS buffers (128 KB), part-granular staging (8 global_load_lds per thread
// per K-tile, issued 2 per phase during the PREVIOUS tile), counted vmcnt(2)
// + s_barrier exactly twice per tile (entry: B+A-even-quarters; mid: A-odd
// quarters) -- vmcnt is per-wave, so every cross-wave landing guarantee is a
// {vmcnt; barrier} pair; no cold drain anywhere.
// Staging order per tile: B p0,p1 | B p2,p3 | A q0,q2 | A q1,q3 (youngest 2
// at every wait point are exactly the ones vmcnt(2) may leave outstanding).
// XOR chunk-swizzle both-sides; bijective XCD swizzle; grid (4,32,gz).
// ---------------------------------------------------------------------------
#define DP_AB 16384           /* u16: 256*64 per matrix per buffer */
#define DP_BUF 32768          /* u16: A+B per buffer (64 KB) */
#define DP_SMEM_BYTES 131072  /* 2 buffers = 128 KB */

template <bool TRIPLE, bool F32OUT>
__global__ __launch_bounds__(512, 1) void gemm_dp(
    const u16* __restrict__ A0, const u16* __restrict__ A1,
    const u16* __restrict__ A2, const u16* __restrict__ B0,
    const u16* __restrict__ B1, const u16* __restrict__ B2,
    float* __restrict__ Cf, u16* __restrict__ C0, u16* __restrict__ C1,
    u16* __restrict__ C2) {
  extern __shared__ __align__(16) u16 smem[];
  // T1: bijective XCD swizzle over flattened grid (x fastest; gridDim=(4,32,z))
  const int nwg = (int)(gridDim.x * gridDim.y * gridDim.z);  // 384 or 128
  const int wg = (int)(blockIdx.x + (blockIdx.y << 2) + (blockIdx.z << 7));
  const int cpx = nwg >> 3;
  const int swz = (wg & 7) * cpx + (wg >> 3);
  const int bx = swz & 3;
  const int by = (swz >> 2) & 31;
  const int bz = swz >> 7;

  const u16* __restrict__ A;
  const u16* __restrict__ Bt;
  u16* __restrict__ Cb;
  if (TRIPLE) {
    switch (bz) {
      case 0: A = A0; Bt = B0; Cb = C0; break;
      case 1: A = A1; Bt = B1; Cb = C1; break;
      default: A = A2; Bt = B2; Cb = C2; break;
    }
  } else {
    A = A0; Bt = B0; Cb = C0;
  }

  const int tid = threadIdx.x;
  const int lane = tid & 63;
  const int wave = tid >> 6;    // 0..7
  const int wm = wave >> 2;     // 0..1 -> rows [wm*128, wm*128+128)
  const int wn = wave & 3;      // 0..3 -> cols [wn*64, wn*64+64)
  const int fr = lane & 15;
  const int fq = lane >> 4;
  const int s8 = fr & 7;
  const int row0 = by * 256;
  const int col0 = bx * 256;
  const int wrow = wm * 128;
  const int wcol = wn * 64;

  // per-lane LDS frag offsets (u16 units), loop-invariant
  int aoff[8][2], boff[4][2];
#pragma unroll
  for (int mi = 0; mi < 8; mi++)
#pragma unroll
    for (int ks = 0; ks < 2; ks++)
      aoff[mi][ks] = (wrow + mi * 16 + fr) * 64 + (((ks * 4 + fq) ^ s8) * 8);
#pragma unroll
  for (int nj = 0; nj < 4; nj++)
#pragma unroll
    for (int ks = 0; ks < 2; ks++)
      boff[nj][ks] = (wcol + nj * 16 + fr) * 64 + (((ks * 4 + fq) ^ s8) * 8);

  // stage one 64-row part (512 x 16B, 1 load/thread); source pre-swizzled so
  // linear LDS dest + swizzled frag read form a consistent involution.
  auto stage_part = [&](const u16* __restrict__ g, u16* __restrict__ dst,
                        int part) {
    int rl = tid >> 3;
    int gch = (tid & 7) ^ (rl & 7);
    __builtin_amdgcn_global_load_lds(
        (const __attribute__((address_space(1))) void*)(
            g + (size_t)(part * 64 + rl) * 1024 + gch * 8),
        (__attribute__((address_space(3))) void*)(dst + part * 4096 + tid * 8),
        16, 0, 0);
  };

  f32x4 acc[8][4];
#pragma unroll
  for (int mi = 0; mi < 8; mi++)
#pragma unroll
    for (int nj = 0; nj < 4; nj++) acc[mi][nj] = (f32x4){0.f, 0.f, 0.f, 0.f};

#define RD_B(KS)                                            \
  _Pragma("unroll") for (int nj = 0; nj < 4; nj++)          \
      bv[nj] = *(const bf16x8*)(sB + boff[nj][KS]);
#define RD_A(OFF, KS)                                       \
  _Pragma("unroll") for (int mi = 0; mi < 4; mi++)          \
      av[mi] = *(const bf16x8*)(sA + aoff[(OFF) + mi][KS]);
#define PH_MFMA(ACCBASE)                                                     \
  __builtin_amdgcn_s_setprio(1);                                             \
  _Pragma("unroll") for (int mi = 0; mi < 4; mi++)                           \
      _Pragma("unroll") for (int nj = 0; nj < 4; nj++)                       \
          acc[(ACCBASE) + mi][nj] = __builtin_amdgcn_mfma_f32_16x16x32_bf16( \
              av[mi], bv[nj], acc[(ACCBASE) + mi][nj], 0, 0, 0);             \
  __builtin_amdgcn_s_setprio(0);

  // prologue: stage tile 0 -> buf 0 (order: B p0..3, A q0, q2, then q1, q3)
  {
    const u16* gA = A + (size_t)row0 * 1024;
    const u16* gB = Bt + (size_t)col0 * 1024;
    u16* dA = smem;
    u16* dB = smem + DP_AB;
    stage_part(gB, dB, 0);
    stage_part(gB, dB, 1);
    stage_part(gB, dB, 2);
    stage_part(gB, dB, 3);
    stage_part(gA, dA, 0);
    stage_part(gA, dA, 2);
    stage_part(gA, dA, 1);
    stage_part(gA, dA, 3);
  }
  asm volatile("s_waitcnt vmcnt(2)" ::: "memory");
  __builtin_amdgcn_s_barrier();

#pragma unroll 2
  for (int t = 0; t < 16; t++) {
    const int d = t & 1;
    const bool st = (t < 15);
    const u16* sA = smem + d * DP_BUF;
    const u16* sB = sA + DP_AB;
    const u16* gA = A + (size_t)row0 * 1024 + (t + 1) * 64;
    const u16* gB = Bt + (size_t)col0 * 1024 + (t + 1) * 64;
    u16* dA = smem + (d ^ 1) * DP_BUF;
    u16* dB = dA + DP_AB;
    bf16x8 av[4], bv[4];
    // ---- phase 0: ks0, mi 0-3 (B ks0 fresh) ----
    if (st) { stage_part(gB, dB, 0); stage_part(gB, dB, 1); }
    RD_B(0);
    RD_A(0, 0);
    PH_MFMA(0);
    // ---- mid sync: own A q1,q3 landed -> collective ----
    if (st)
      asm volatile("s_waitcnt vmcnt(2)" ::: "memory");
    else
      asm volatile("s_waitcnt vmcnt(0)" ::: "memory");
    __builtin_amdgcn_s_barrier();
    __builtin_amdgcn_sched_barrier(0);
    // ---- phase 1: ks0, mi 4-7 (reuse bv) ----
    if (st) { stage_part(gB, dB, 2); stage_part(gB, dB, 3); }
    RD_A(4, 0);
    PH_MFMA(4);
    __builtin_amdgcn_sched_barrier(0);
    // ---- phase 2: ks1, mi 0-3 (B ks1 fresh) ----
    if (st) { stage_part(gA, dA, 0); stage_part(gA, dA, 2); }
    RD_B(1);
    RD_A(0, 1);
    PH_MFMA(0);
    __builtin_amdgcn_sched_barrier(0);
    // ---- phase 3: ks1, mi 4-7 ----
    if (st) { stage_part(gA, dA, 1); stage_part(gA, dA, 3); }
    RD_A(4, 1);
    PH_MFMA(4);
    // ---- boundary: next tile's B + A q0,q2 landed -> collective ----
    if (st) {
      asm volatile("s_waitcnt vmcnt(2)" ::: "memory");
      __builtin_amdgcn_s_barrier();
    }
  }
#undef RD_B
#undef RD_A
#undef PH_MFMA

#pragma unroll
  for (int mi = 0; mi < 8; mi++) {
    int grow = row0 + wrow + mi * 16 + fq * 4;
#pragma unroll
    for (int nj = 0; nj < 4; nj++) {
      int gcol = col0 + wcol + nj * 16 + fr;
#pragma unroll
      for (int r = 0; r < 4; r++) {
        if (F32OUT)
          Cf[(size_t)(grow + r) * 1024 + gcol] = acc[mi][nj][r];
        else
          Cb[(size_t)(grow + r) * 1024 + gcol] = f2b(acc[mi][nj][r]);
      }
    }
  }
}

// ---------------------------------------------------------------------------
// 3. blend via MFMA (fused x/xx/tm* epilogue); all four outputs bf16.
// ---------------------------------------------------------------------------
__global__ __launch_bounds__(256) void blend_mfma(
    const u16* __restrict__ mb, const u16* __restrict__ w2T,
    const float* __restrict__ x, const float* __restrict__ xx,
    const float* __restrict__ tmw, const float* __restrict__ tmk,
    const float* __restrict__ tmv, const float* __restrict__ tmr,
    u16* __restrict__ xwb, u16* __restrict__ xkb, u16* __restrict__ xvb,
    u16* __restrict__ xrb) {
  __shared__ u16 mS[64 * 136];
  __shared__ u16 wS[64 * 136];
  const int tid = threadIdx.x;
  const int lane = tid & 63;
  const int w = tid >> 6;
  const int fr = lane & 15;
  const int fq = lane >> 4;
  const int c0 = blockIdx.x * 64;
  const int bt0 = blockIdx.y * 64;

#pragma unroll
  for (int it = 0; it < 4; it++) {
    int idx = tid + it * 256;  // 0..1023
    int r = idx >> 4, c8 = (idx & 15) * 8;
    bf16x8 v = *(const bf16x8*)(mb + (size_t)(bt0 + r) * 128 + c8);
    *(bf16x4*)(mS + r * 136 + c8) = __builtin_shufflevector(v, v, 0, 1, 2, 3);
    *(bf16x4*)(mS + r * 136 + c8 + 4) = __builtin_shufflevector(v, v, 4, 5, 6, 7);
    bf16x8 u = *(const bf16x8*)(w2T + (size_t)(c0 + r) * 128 + c8);
    *(bf16x4*)(wS + r * 136 + c8) = __builtin_shufflevector(u, u, 0, 1, 2, 3);
    *(bf16x4*)(wS + r * 136 + c8 + 4) = __builtin_shufflevector(u, u, 4, 5, 6, 7);
  }
  __syncthreads();

  f32x4 acc[4][4];  // [col-tile j][f]
#pragma unroll
  for (int j = 0; j < 4; j++)
#pragma unroll
    for (int f = 0; f < 4; f++) acc[j][f] = (f32x4){0.f, 0.f, 0.f, 0.f};

#pragma unroll
  for (int f = 0; f < 4; f++) {
    bf16x8 aA = ldfrag(mS + (w * 16 + fr) * 136 + f * 32 + fq * 8);
#pragma unroll
    for (int j = 0; j < 4; j++) {
      bf16x8 bB = ldfrag(wS + (j * 16 + fr) * 136 + f * 32 + fq * 8);
      acc[j][f] = __builtin_amdgcn_mfma_f32_16x16x32_bf16(aA, bB, acc[j][f], 0, 0, 0);
    }
  }

#pragma unroll
  for (int j = 0; j < 4; j++) {
    int c = c0 + j * 16 + fr;
    float w_ = tmw[c], k_ = tmk[c], v_ = tmv[c], r_ = tmr[c];
#pragma unroll
    for (int rr = 0; rr < 4; rr++) {
      int bt = bt0 + w * 16 + fq * 4 + rr;
      size_t g = (size_t)bt * 1024 + c;
      float xv_ = x[g], dx = xx[g];
      xwb[g] = f2b(xv_ + dx * (w_ + acc[j][0][rr]));
      xkb[g] = f2b(xv_ + dx * (k_ + acc[j][1][rr]));
      xvb[g] = f2b(xv_ + dx * (v_ + acc[j][2][rr]));
      xrb[g] = f2b(xv_ + dx * (r_ + acc[j][3][rr]));
    }
  }
}

// ---------------------------------------------------------------------------
// 5a. decay reduce: dw2r f32 [64][16], tdr f32 [16], dw2rbT bf16 [16][64]
// ---------------------------------------------------------------------------
__global__ __launch_bounds__(256) void dw2r_kernel(const float* __restrict__ dw2,
                                                   const float* __restrict__ td,
                                                   float* __restrict__ dw2r,
                                                   float* __restrict__ tdr,
                                                   u16* __restrict__ dw2rbT) {
  int idx = blockIdx.x * 256 + threadIdx.x;
  if (idx < 1024) {
    int j = idx >> 4, h = idx & 15;
    float s = 0.f;
    for (int n = 0; n < 64; n++) s += dw2[(size_t)j * 1024 + h * 64 + n];
    float m = s * (1.f / 64.f);
    dw2r[j * 16 + h] = m;
    dw2rbT[h * 64 + j] = f2b(m);
  }
  if (idx < 16) {
    float s = 0.f;
    for (int n = 0; n < 64; n++) s += td[idx * 64 + n];
    tdr[idx] = s * (1.f / 64.f);
  }
}

// ---------------------------------------------------------------------------
// 5b. fused decay GEMM: h1 = tanh(xw @ d1) via MFMA (K=1024), then
//     wlog = -exp(tdr + h1 @ dw2r) via a second 2-step MFMA. 64-row tiles.
// ---------------------------------------------------------------------------
__global__ __launch_bounds__(256) void decay_mfma(const u16* __restrict__ xwb,
                                                  const u16* __restrict__ d1T,
                                                  const u16* __restrict__ dw2rbT,
                                                  const float* __restrict__ tdr,
                                                  float* __restrict__ wlog) {
  __shared__ u16 As[64 * 32];
  __shared__ u16 Bs[64 * 32];
  __shared__ u16 h1S[64 * 72];
  __shared__ u16 dwS[16 * 72];
  const int tid = threadIdx.x;
  const int lane = tid & 63;
  const int w = tid >> 6;
  const int fr = lane & 15;
  const int fq = lane >> 4;
  const int bt0 = blockIdx.x * 64;

#pragma unroll
  for (int it = 0; it < 4; it++) {
    int idx = tid + it * 256;
    int r = idx >> 6, c = idx & 63;
    dwS[r * 72 + c] = dw2rbT[r * 64 + c];
  }

  f32x4 acc[4];
#pragma unroll
  for (int j = 0; j < 4; j++) acc[j] = (f32x4){0.f, 0.f, 0.f, 0.f};

  const int ra = tid >> 2, ca = (tid & 3) * 8;
  for (int k0 = 0; k0 < 1024; k0 += 32) {
    __builtin_amdgcn_global_load_lds(
        (const __attribute__((address_space(1))) void*)(xwb + (size_t)(bt0 + ra) * 1024 + k0 + ca),
        (__attribute__((address_space(3))) void*)(As + tid * 8), 16, 0, 0);
    __builtin_amdgcn_global_load_lds(
        (const __attribute__((address_space(1))) void*)(d1T + (size_t)ra * 1024 + k0 + ca),
        (__attribute__((address_space(3))) void*)(Bs + tid * 8), 16, 0, 0);
    __syncthreads();
    bf16x8 aA = *(const bf16x8*)(As + ((w * 16 + fr) * 32 + fq * 8));
#pragma unroll
    for (int j = 0; j < 4; j++) {
      bf16x8 bB = *(const bf16x8*)(Bs + ((j * 16 + fr) * 32 + fq * 8));
      acc[j] = __builtin_amdgcn_mfma_f32_16x16x32_bf16(aA, bB, acc[j], 0, 0, 0);
    }
    __syncthreads();
  }
#pragma unroll
  for (int j = 0; j < 4; j++)
#pragma unroll
    for (int rr = 0; rr < 4; rr++)
      h1S[(w * 16 + fq * 4 + rr) * 72 + j * 16 + fr] = f2b(tanhf(acc[j][rr]));
  __syncthreads();

  f32x4 a2 = (f32x4){0.f, 0.f, 0.f, 0.f};
#pragma unroll
  for (int ks = 0; ks < 2; ks++) {
    bf16x8 aA = ldfrag(h1S + (w * 16 + fr) * 72 + ks * 32 + fq * 8);
    bf16x8 bB = ldfrag(dwS + fr * 72 + ks * 32 + fq * 8);
    a2 = __builtin_amdgcn_mfma_f32_16x16x32_bf16(aA, bB, a2, 0, 0, 0);
  }
  float tdv = tdr[fr];
#pragma unroll
  for (int rr = 0; rr < 4; rr++) {
    int bt = bt0 + w * 16 + fq * 4 + rr;
    int b = bt >> 11, tl = bt & 2047;
    wlog[((size_t)(b * 16 + fr)) * 2048 + tl] = -__expf(tdv + a2[rr]);
  }
}

// ---------------------------------------------------------------------------
// 7. per-chunk scan
// ---------------------------------------------------------------------------
__global__ __launch_bounds__(256) void wprep_kernel(const float* __restrict__ wlog,
                                                    float* __restrict__ cum,
                                                    float* __restrict__ excl,
                                                    float* __restrict__ wsl) {
  int bid = blockIdx.x;
  int c = bid & 7, bh = bid >> 3;
  int q = threadIdx.x;
  float v = wlog[(size_t)bh * 2048 + c * 256 + q];
  __shared__ float s[256];
  s[q] = v;
  float val = v;
  for (int off = 1; off < 256; off <<= 1) {
    __syncthreads();
    float t = (q >= off) ? s[q - off] : 0.f;
    __syncthreads();
    val += t;
    s[q] = val;
  }
  __syncthreads();
  float total = s[255];
  cum[(size_t)bid * 256 + q] = val;
  excl[(size_t)bid * 256 + q] = val - v;
  if (q == 0) wsl[bid] = total;
}

// ---------------------------------------------------------------------------
// kvtrans2: per-head transpose of bf16 k,v (k scaled by w_inter on output),
// plus diag[b,h,t] = sum_n r*fa*k (raw k), via full-wave reduce.
// ---------------------------------------------------------------------------
__global__ __launch_bounds__(256) void kvtrans2_kernel(
    const u16* __restrict__ vb, const u16* __restrict__ kb,
    const u16* __restrict__ rb, const float* __restrict__ faaaa,
    const float* __restrict__ cum, const float* __restrict__ wsl,
    u16* __restrict__ vT, u16* __restrict__ kTw, float* __restrict__ diagG) {
  int tt = blockIdx.x;  // t-tile 0..31
  int bh = blockIdx.y;  // 0..63
  int b = bh >> 4, h = bh & 15;
  int cc = tt >> 2;
  int bidc = bh * 8 + cc;
  __shared__ float tv[64][65];
  __shared__ float tk[64][65];
  __shared__ float wfac[64];
  __shared__ float faS[64];
  const int tid = threadIdx.x;
  float wslog = wsl[bidc];
  if (tid < 64) {
    wfac[tid] = __expf(wslog - cum[(size_t)bidc * 256 + (tt & 3) * 64 + tid]);
    faS[tid] = faaaa[h * 64 + tid];
  }
  __syncthreads();
  const int m = tid & 63;
  float fam = faS[m];
#pragma unroll
  for (int it = 0; it < 16; it++) {
    int r = it * 4 + (tid >> 6);
    size_t g = ((size_t)(b * TT + tt * 64 + r)) * CC + h * 64 + m;
    float vraw = b2f(vb[g]);
    float kraw = b2f(kb[g]);
    float rraw = b2f(rb[g]);
    tv[r][m] = vraw;
    tk[r][m] = kraw;
    float s = rraw * fam * kraw;
    s += __shfl_xor(s, 1);
    s += __shfl_xor(s, 2);
    s += __shfl_xor(s, 4);
    s += __shfl_xor(s, 8);
    s += __shfl_xor(s, 16);
    s += __shfl_xor(s, 32);
    if (m == 0) diagG[(size_t)bh * 2048 + tt * 64 + r] = s;
  }
  __syncthreads();
#pragma unroll
  for (int it = 0; it < 16; it++) {
    int idx = it * 256 + tid;
    int mm = idx >> 6, tl = idx & 63;
    size_t o = ((size_t)(bh * 64 + mm)) * TT + tt * 64 + tl;
    vT[o] = f2b(tv[tl][mm]);
    kTw[o] = f2b(tk[tl][mm] * wfac[tl]);
  }
}

// ---------------------------------------------------------------------------
// 8a. kv via MFMA
// ---------------------------------------------------------------------------
__global__ __launch_bounds__(256) void kv_mfma(const u16* __restrict__ kTw,
                                               const u16* __restrict__ vT,
                                               float* __restrict__ kvb) {
  int bid = blockIdx.x;
  int c = bid & 7, bh = bid >> 3;
  __shared__ u16 kS[64 * 72];
  __shared__ u16 vS[64 * 72];
  const int tid = threadIdx.x;
  const int lane = tid & 63;
  const int w = tid >> 6;
  const int fr = lane & 15;
  const int fq = lane >> 4;
  f32x4 acc[4];
#pragma unroll
  for (int j = 0; j < 4; j++) acc[j] = (f32x4){0.f, 0.f, 0.f, 0.f};
  const size_t base = (size_t)bh * 64 * TT + c * QQ;
  for (int qt = 0; qt < 4; qt++) {
    __syncthreads();
    stage_tile(kTw, base + qt * 64, TT, tid, kS);
    stage_tile(vT, base + qt * 64, TT, tid, vS);
    __syncthreads();
#pragma unroll
    for (int ks = 0; ks < 2; ks++) {
      bf16x8 aA = ldfrag(kS + (w * 16 + fr) * 72 + ks * 32 + fq * 8);
#pragma unroll
      for (int j = 0; j < 4; j++) {
        bf16x8 bB = ldfrag(vS + (j * 16 + fr) * 72 + ks * 32 + fq * 8);
        acc[j] = __builtin_amdgcn_mfma_f32_16x16x32_bf16(aA, bB, acc[j], 0, 0, 0);
      }
    }
  }
#pragma unroll
  for (int j = 0; j < 4; j++)
#pragma unroll
    for (int rr = 0; rr < 4; rr++)
      kvb[(size_t)bid * 4096 + (w * 16 + fq * 4 + rr) * 64 + j * 16 + fr] = acc[j][rr];
}

// ---------------------------------------------------------------------------
// 8b. sequential state scan over chunks
// ---------------------------------------------------------------------------
__global__ __launch_bounds__(256) void scan_kernel(const float* __restrict__ kvb,
                                                   const float* __restrict__ wsl,
                                                   float* __restrict__ st) {
  int bh = blockIdx.x;
  int tid = threadIdx.x;
  float s[16];
#pragma unroll
  for (int i = 0; i < 16; i++) s[i] = 0.f;
  for (int c = 0; c < 8; c++) {
    int bid = bh * 8 + c;
    float w = __expf(wsl[bid]);
#pragma unroll
    for (int i = 0; i < 16; i++) {
      size_t e = (size_t)bid * 4096 + i * 256 + tid;
      st[e] = s[i];
      s[i] = w * s[i] + kvb[e];
    }
  }
}

// ---------------------------------------------------------------------------
// 9. MFMA fused attention. Mask via factored exp tables:
// exp(excl[q]-cum[k]) = exp(excl[q]-cc) * exp(cc-cum[k]), cc = cum[127]
// (both exponents bounded ~|47| -> no overflow; true product <= 1).
// Diagonal read from diagG (precomputed in kvtrans2).
// ---------------------------------------------------------------------------
__global__ __launch_bounds__(256) void attn_mfma(
    const u16* __restrict__ rb, const u16* __restrict__ kb,
    const u16* __restrict__ vT, const float* __restrict__ stg,
    const float* __restrict__ cum, const float* __restrict__ excl,
    const float* __restrict__ diagG, float* __restrict__ y) {
  int bid = blockIdx.x;
  int c = bid & 7, bh = bid >> 3;
  int b = bh >> 4, h = bh & 15;
  __shared__ u16 rt[64 * 72];
  __shared__ u16 kt[64 * 72];
  __shared__ u16 vt[64 * 72];
  __shared__ u16 pt[64 * 72];
  __shared__ u16 stT[64 * 72];
  __shared__ float cumS[256], exS[256], diagS[256], ekS[256];

  const int tid = threadIdx.x;
  const int lane = tid & 63;
  const int w = tid >> 6;
  const int fr = lane & 15;
  const int fq = lane >> 4;

  cumS[tid] = cum[(size_t)bid * 256 + tid];
  exS[tid] = excl[(size_t)bid * 256 + tid];
  diagS[tid] = diagG[(size_t)bh * 2048 + c * 256 + tid];
#pragma unroll
  for (int it = 0; it < 16; it++) {
    int idx = tid + it * 256;
    int n = idx >> 6, mm = idx & 63;
    stT[mm * 72 + n] = f2b(stg[(size_t)bid * 4096 + idx]);
  }
  __syncthreads();
  const float ccm = cumS[127];
  ekS[tid] = __expf(ccm - cumS[tid]);

  const size_t rowbase = ((size_t)b * TT + c * QQ) * CC + h * 64;
  const size_t vbase0 = (size_t)bh * 64 * TT + c * QQ;

  for (int qt = 0; qt < 4; qt++) {
    __syncthreads();
    stage_tile(rb, rowbase + (size_t)(qt * 64) * CC, CC, tid, rt);
    __syncthreads();

    f32x4 acc[4];
#pragma unroll
    for (int jm = 0; jm < 4; jm++) acc[jm] = (f32x4){0.f, 0.f, 0.f, 0.f};
    bf16x8 rA[2];
    rA[0] = ldfrag(rt + (w * 16 + fr) * 72 + fq * 8);
    rA[1] = ldfrag(rt + (w * 16 + fr) * 72 + 32 + fq * 8);
#pragma unroll
    for (int ks = 0; ks < 2; ks++)
#pragma unroll
      for (int jm = 0; jm < 4; jm++) {
        bf16x8 bB = ldfrag(stT + (jm * 16 + fr) * 72 + ks * 32 + fq * 8);
        acc[jm] = __builtin_amdgcn_mfma_f32_16x16x32_bf16(rA[ks], bB, acc[jm], 0, 0, 0);
      }
    int ql0 = w * 16 + fq * 4;
    float er[4], eqc[4];
#pragma unroll
    for (int rr = 0; rr < 4; rr++) {
      float ex = exS[qt * 64 + ql0 + rr];
      er[rr] = __expf(ex);
      eqc[rr] = __expf(ex - ccm);
    }
#pragma unroll
    for (int jm = 0; jm < 4; jm++)
#pragma unroll
      for (int rr = 0; rr < 4; rr++) acc[jm][rr] *= er[rr];

    for (int kti = 0; kti <= qt; kti++) {
      __syncthreads();
      stage_tile(kb, rowbase + (size_t)(kti * 64) * CC, CC, tid, kt);
      stage_tile(vT, vbase0 + (size_t)(kti * 64), TT, tid, vt);
      __syncthreads();

      f32x4 sacc[4];
#pragma unroll
      for (int jj = 0; jj < 4; jj++) sacc[jj] = (f32x4){0.f, 0.f, 0.f, 0.f};
#pragma unroll
      for (int ks = 0; ks < 2; ks++)
#pragma unroll
        for (int jj = 0; jj < 4; jj++) {
          bf16x8 bB = ldfrag(kt + (jj * 16 + fr) * 72 + ks * 32 + fq * 8);
          sacc[jj] = __builtin_amdgcn_mfma_f32_16x16x32_bf16(rA[ks], bB, sacc[jj], 0, 0, 0);
        }
#pragma unroll
      for (int jj = 0; jj < 4; jj++) {
        int kcol = kti * 64 + jj * 16 + fr;
        float ek = ekS[kcol];
#pragma unroll
        for (int rr = 0; rr < 4; rr++) {
          int qrow = qt * 64 + ql0 + rr;
          float vsc;
          if (kcol < qrow)
            vsc = sacc[jj][rr] * eqc[rr] * ek;
          else if (kcol == qrow)
            vsc = diagS[qrow];
          else
            vsc = 0.f;
          pt[(ql0 + rr) * 72 + jj * 16 + fr] = f2b(vsc);
        }
      }
      __syncthreads();
#pragma unroll
      for (int ks = 0; ks < 2; ks++) {
        bf16x8 pA = ldfrag(pt + (w * 16 + fr) * 72 + ks * 32 + fq * 8);
#pragma unroll
        for (int jm = 0; jm < 4; jm++) {
          bf16x8 vB = ldfrag(vt + (jm * 16 + fr) * 72 + ks * 32 + fq * 8);
          acc[jm] = __builtin_amdgcn_mfma_f32_16x16x32_bf16(pA, vB, acc[jm], 0, 0, 0);
        }
      }
    }
    int qg0 = qt * 64 + w * 16 + fq * 4;
#pragma unroll
    for (int jm = 0; jm < 4; jm++)
#pragma unroll
      for (int rr = 0; rr < 4; rr++)
        y[rowbase + (size_t)(qg0 + rr) * CC + jm * 16 + fr] = acc[jm][rr];
  }
}

// ---------------------------------------------------------------------------
// 10. LayerNorm over C -> bf16
// ---------------------------------------------------------------------------
__global__ __launch_bounds__(256) void ln_kernel(const float* __restrict__ y,
                                                 const float* __restrict__ g,
                                                 const float* __restrict__ bta,
                                                 u16* __restrict__ out) {
  __shared__ float red[8];
  int bt = blockIdx.x;
  int tid = threadIdx.x;
  float v[4];
  float s = 0.f;
#pragma unroll
  for (int i = 0; i < 4; i++) {
    v[i] = y[(size_t)bt * 1024 + i * 256 + tid];
    s += v[i];
  }
#pragma unroll
  for (int off = 32; off > 0; off >>= 1) s += __shfl_down(s, off);
  if ((tid & 63) == 0) red[tid >> 6] = s;
  __syncthreads();
  if (tid == 0) red[4] = red[0] + red[1] + red[2] + red[3];
  __syncthreads();
  float mu = red[4] * (1.f / 1024.f);
  float s2 = 0.f;
#pragma unroll
  for (int i = 0; i < 4; i++) {
    float d = v[i] - mu;
    s2 += d * d;
  }
#pragma unroll
  for (int off = 32; off > 0; off >>= 1) s2 += __shfl_down(s2, off);
  __syncthreads();
  if ((tid & 63) == 0) red[tid >> 6] = s2;
  __syncthreads();
  if (tid == 0) red[5] = red[0] + red[1] + red[2] + red[3];
  __syncthreads();
  float var = red[5] * (1.f / 1024.f);
  float rstd = rsqrtf(var + 1e-5f);
#pragma unroll
  for (int i = 0; i < 4; i++) {
    int c = i * 256 + tid;
    out[(size_t)bt * 1024 + c] = f2b((v[i] - mu) * rstd * g[c] + bta[c]);
  }
}

// ---------------------------------------------------------------------------
extern "C" void kernel_launch(void* const* d_in, const int* in_sizes, int n_in,
                              void* d_out, int out_size, void* d_ws,
                              size_t ws_size, hipStream_t stream) {
  const float* x = (const float*)d_in[0];
  const float* tmx = (const float*)d_in[1];
  const float* tmw = (const float*)d_in[2];
  const float* tmk = (const float*)d_in[3];
  const float* tmv = (const float*)d_in[4];
  const float* tmr = (const float*)d_in[5];
  const float* maa_w1 = (const float*)d_in[6];
  const float* maa_w2 = (const float*)d_in[7];
  const float* decay_w1 = (const float*)d_in[8];
  const float* decay_w2 = (const float*)d_in[9];
  const float* time_decay = (const float*)d_in[10];
  const float* faaaa = (const float*)d_in[11];
  const float* Wr = (const float*)d_in[12];
  const float* Wk = (const float*)d_in[13];
  const float* Wv = (const float*)d_in[14];
  const float* Wo = (const float*)d_in[15];
  const float* lng = (const float*)d_in[16];
  const float* lnb = (const float*)d_in[17];
  float* out = (float*)d_out;
  float* ws = (float*)d_ws;

  const size_t S = (size_t)BT * CC;  // 8388608

  // f32 region
  float* xx = ws;                     // mix out -> blend in; later y_ (attn out)
  float* dw2r = ws + S;               // 1024
  float* tdr = dw2r + 1024;           // pad to 1024
  float* wlog = tdr + 1024;           // 131072
  float* cum = wlog + 131072;
  float* excl = cum + 131072;
  float* wsl = excl + 131072;         // pad to 1024
  float* diagG = wsl + 1024;          // 131072
  float* kvb = diagG + 131072;        // 512*4096
  float* stb = kvb + (size_t)512 * 4096;
  float* fend = stb + (size_t)512 * 4096;
  // bf16 region (u16)
  u16* xxxb = (u16*)fend;             // mix out -> maa GEMM in -> vT
  u16* mb = xxxb + S;                 // BT*128
  u16* xkb = mb + (size_t)BT * 128;   // blend out -> gemm_dp in -> ylnb
  u16* xvb = xkb + S;                 // blend out -> gemm_dp in
  u16* xrb = xvb + S;                 // blend out -> gemm_dp in -> kTw
  u16* xwb = xrb + S;                 // blend out -> decay_mfma in
  u16* rb16 = xwb + S;                // gemm_dp out
  u16* kb16 = rb16 + S;               // gemm_dp out
  u16* Vb = kb16 + S;                 // gemm_dp out
  u16* Wrt = Vb + S;
  u16* Wkt = Wrt + (size_t)1024 * 1024;
  u16* Wvt = Wkt + (size_t)1024 * 1024;
  u16* Wot = Wvt + (size_t)1024 * 1024;
  u16* w1T = Wot + (size_t)1024 * 1024;   // [128][1024]
  u16* w2T = w1T + (size_t)128 * 1024;    // [1024][128]
  u16* d1T = w2T + (size_t)1024 * 128;    // [64][1024]
  u16* dw2rbT = d1T + (size_t)64 * 1024;  // [16][64]
  // aliases (stream-ordered reuse)
  u16* vT = xxxb;   // after maa GEMM consumed xxxb
  u16* kTw = xrb;   // after gemm_dp consumed xrb
  float* y_ = xx;   // after blend consumed xx
  u16* ylnb = xkb;  // after gemm_dp consumed xkb

  // allow 128 KB dynamic LDS for the deep-pipelined GEMMs (once per process)
  static bool attr_done = false;
  if (!attr_done) {
    hipFuncSetAttribute((const void*)gemm_dp<true, false>,
                        hipFuncAttributeMaxDynamicSharedMemorySize, DP_SMEM_BYTES);
    hipFuncSetAttribute((const void*)gemm_dp<false, true>,
                        hipFuncAttributeMaxDynamicSharedMemorySize, DP_SMEM_BYTES);
    attr_done = true;
  }

  cvt_wT<<<dim3(16, 16, 4), 256, 0, stream>>>(Wr, Wk, Wv, Wo, Wrt, Wkt, Wvt, Wot);
  cvt_T<<<dim3(2, 16), 256, 0, stream>>>(maa_w1, w1T, 1024, 128);
  cvt_T<<<dim3(16, 2), 256, 0, stream>>>(maa_w2, w2T, 128, 1024);
  cvt_T<<<dim3(1, 16), 256, 0, stream>>>(decay_w1, d1T, 1024, 64);
  dw2r_kernel<<<4, 256, 0, stream>>>(decay_w2, time_decay, dw2r, tdr, dw2rbT);
  mix_kernel<<<8192, 256, 0, stream>>>(x, tmx, xx, xxxb);
  gemm_bt_mfma<true><<<dim3(1, 64), 256, 0, stream>>>(xxxb, w1T, nullptr, mb, BT, 128, CC);
  blend_mfma<<<dim3(16, 128), 256, 0, stream>>>(mb, w2T, x, xx, tmw, tmk, tmv,
                                                tmr, xwb, xkb, xvb, xrb);
  decay_mfma<<<128, 256, 0, stream>>>(xwb, d1T, dw2rbT, tdr, wlog);
  wprep_kernel<<<512, 256, 0, stream>>>(wlog, cum, excl, wsl);
  // fused r/k/v projections: deep-pipelined GEMM v4 (256^2, 8 waves, 128x64/wave)
  gemm_dp<true, false><<<dim3(4, 32, 3), 512, DP_SMEM_BYTES, stream>>>(
      xrb, xkb, xvb, Wrt, Wkt, Wvt, nullptr, rb16, kb16, Vb);
  kvtrans2_kernel<<<dim3(32, 64), 256, 0, stream>>>(Vb, kb16, rb16, faaaa, cum,
                                                    wsl, vT, kTw, diagG);
  kv_mfma<<<512, 256, 0, stream>>>(kTw, vT, kvb);
  scan_kernel<<<64, 256, 0, stream>>>(kvb, wsl, stb);
  attn_mfma<<<512, 256, 0, stream>>>(rb16, kb16, vT, stb, cum, excl, diagG, y_);
  ln_kernel<<<BT, 256, 0, stream>>>(y_, lng, lnb, ylnb);
  // output projection: same deep-pipelined GEMM, f32 out
  gemm_dp<false, true><<<dim3(4, 32, 1), 512, DP_SMEM_BYTES, stream>>>(
      ylnb, nullptr, nullptr, Wot, nullptr, nullptr, out, nullptr, nullptr,
      nullptr);
}

// Round 5
// 365.001 us; speedup vs baseline: 1.1593x; 1.1593x over previous
//
#include <hip/hip_runtime.h>
#include <math.h>

// B=4, T=2048, C=1024, H=16, N=64, Q=256, nc=8, BT=8192
#define BB 4
#define TT 2048
#define CC 1024
#define HH 16
#define NN 64
#define QQ 256
#define NCH 8
#define BT 8192

typedef unsigned short u16;
typedef __attribute__((ext_vector_type(8))) short bf16x8;
typedef __attribute__((ext_vector_type(4))) short bf16x4;
typedef __attribute__((ext_vector_type(4))) float f32x4;
typedef __attribute__((ext_vector_type(4))) u16 u16x4;

// f32 -> bf16 bits, round-to-nearest-even
__device__ inline u16 f2b(float x) {
  union { float f; unsigned u; } v;
  v.f = x;
  unsigned r = v.u + 0x7FFFu + ((v.u >> 16) & 1u);
  return (u16)(r >> 16);
}
__device__ inline float b2f(u16 u) {
  union { unsigned u; float f; } v;
  v.u = ((unsigned)u) << 16;
  return v.f;
}
// 16B fragment from padded LDS row via two 8B loads (conflict-friendly)
__device__ inline bf16x8 ldfrag(const u16* p) {
  bf16x4 lo = *(const bf16x4*)p;
  bf16x4 hi = *(const bf16x4*)(p + 4);
  return __builtin_shufflevector(lo, hi, 0, 1, 2, 3, 4, 5, 6, 7);
}
// stage 64x64 bf16 tile (global pitch `pitch` u16) into LDS stride-72
__device__ inline void stage_tile(const u16* __restrict__ g, size_t base,
                                  int pitch, int tid, u16* __restrict__ lds) {
#pragma unroll
  for (int it = 0; it < 2; it++) {
    int cidx = tid + it * 256;  // 0..511
    int r = cidx >> 3, c8 = (cidx & 7) * 8;
    bf16x8 v = *(const bf16x8*)(g + base + (size_t)r * pitch + c8);
    *(bf16x4*)(lds + r * 72 + c8) = __builtin_shufflevector(v, v, 0, 1, 2, 3);
    *(bf16x4*)(lds + r * 72 + c8 + 4) = __builtin_shufflevector(v, v, 4, 5, 6, 7);
  }
}

// ---------------------------------------------------------------------------
// 1. time-shift mix: xxx -> bf16 only (xx recomputed inline in blend)
// ---------------------------------------------------------------------------
__global__ __launch_bounds__(256) void mix_kernel(const float* __restrict__ x,
                                                  const float* __restrict__ tmx,
                                                  u16* __restrict__ xxxb) {
  size_t e = ((size_t)blockIdx.x * 256 + threadIdx.x) * 4;
  int c = (int)(e & 1023);
  size_t row = e >> 10;
  int t = (int)(row & 2047);
  float4 xv = *(const float4*)(x + e);
  float4 pv = make_float4(0.f, 0.f, 0.f, 0.f);
  if (t > 0) pv = *(const float4*)(x + e - 1024);
  float4 d = make_float4(pv.x - xv.x, pv.y - xv.y, pv.z - xv.z, pv.w - xv.w);
  u16x4 o;
  o.x = f2b(xv.x + d.x * tmx[c + 0]);
  o.y = f2b(xv.y + d.y * tmx[c + 1]);
  o.z = f2b(xv.z + d.z * tmx[c + 2]);
  o.w = f2b(xv.w + d.w * tmx[c + 3]);
  *(u16x4*)(xxxb + e) = o;
}

// ---------------------------------------------------------------------------
// weight f32[k][n] (1024x1024) -> bf16 transposed Wt[n][k]
// ---------------------------------------------------------------------------
__global__ __launch_bounds__(256) void cvt_wT(const float* __restrict__ W0,
                                              const float* __restrict__ W1,
                                              const float* __restrict__ W2,
                                              const float* __restrict__ W3,
                                              u16* __restrict__ O0,
                                              u16* __restrict__ O1,
                                              u16* __restrict__ O2,
                                              u16* __restrict__ O3) {
  const float* W;
  u16* O;
  switch (blockIdx.z) {
    case 0: W = W0; O = O0; break;
    case 1: W = W1; O = O1; break;
    case 2: W = W2; O = O2; break;
    default: W = W3; O = O3; break;
  }
  __shared__ float t[64][65];
  int bx = blockIdx.x * 64;
  int by = blockIdx.y * 64;
#pragma unroll
  for (int it = 0; it < 16; it++) {
    int idx = it * 256 + threadIdx.x;
    int r = idx >> 6, c = idx & 63;
    t[r][c] = W[(size_t)(by + r) * 1024 + bx + c];
  }
  __syncthreads();
#pragma unroll
  for (int it = 0; it < 16; it++) {
    int idx = it * 256 + threadIdx.x;
    int n = idx >> 6, k = idx & 63;
    O[(size_t)(bx + n) * 1024 + by + k] = f2b(t[k][n]);
  }
}

// ---------------------------------------------------------------------------
// merged transpose+cvt for the three small weights (one launch):
//   z=0: maa_w1 f32[1024][128] -> w1T bf16[128][1024]
//   z=1: maa_w2 f32[128][1024] -> w2T bf16[1024][128]
//   z=2: decay_w1 f32[1024][64] -> d1T bf16[64][1024]
// grid (16,16,3); out-of-range tiles return immediately.
// ---------------------------------------------------------------------------
__global__ __launch_bounds__(256) void cvt3_T(const float* __restrict__ w1,
                                              const float* __restrict__ w2,
                                              const float* __restrict__ d1,
                                              u16* __restrict__ o1,
                                              u16* __restrict__ o2,
                                              u16* __restrict__ o3) {
  const float* in;
  u16* out;
  int R, C;
  switch (blockIdx.z) {
    case 0: in = w1; out = o1; R = 1024; C = 128; break;
    case 1: in = w2; out = o2; R = 128; C = 1024; break;
    default: in = d1; out = o3; R = 1024; C = 64; break;
  }
  int c0 = blockIdx.x * 64, r0 = blockIdx.y * 64;
  if (c0 >= C || r0 >= R) return;
  __shared__ float t[64][65];
#pragma unroll
  for (int it = 0; it < 16; it++) {
    int idx = it * 256 + threadIdx.x;
    int r = idx >> 6, c = idx & 63;
    t[r][c] = in[(size_t)(r0 + r) * C + c0 + c];
  }
  __syncthreads();
#pragma unroll
  for (int it = 0; it < 16; it++) {
    int idx = it * 256 + threadIdx.x;
    int c = idx >> 6, r = idx & 63;
    out[(size_t)(c0 + c) * R + r0 + r] = f2b(t[r][c]);
  }
}

// ---------------------------------------------------------------------------
// maa GEMM: mb = tanh(xxx @ w1) : A[8192][1024] x w1T[128][1024] -> [8192][128]
// 64-row x 128-col tiles -> grid 128 blocks (2x the old (1,64) launch).
// 256 threads = 4 waves; wave w owns cols [w*32, w*32+32). m97-style K loop.
// ---------------------------------------------------------------------------
__global__ __launch_bounds__(256) void gemm_maa(const u16* __restrict__ A,
                                                const u16* __restrict__ Bt,
                                                u16* __restrict__ Cb) {
  __shared__ u16 As[64 * 32];
  __shared__ u16 Bs[128 * 32];
  const int tid = threadIdx.x;
  const int lane = tid & 63;
  const int wave = tid >> 6;
  const int wc = wave * 32;
  const int fr = lane & 15;
  const int fq = lane >> 4;
  const int row0 = blockIdx.x * 64;

  f32x4 acc[4][2];
#pragma unroll
  for (int i = 0; i < 4; i++)
#pragma unroll
    for (int j = 0; j < 2; j++) acc[i][j] = (f32x4){0.f, 0.f, 0.f, 0.f};

  const int ra = tid >> 2, ca = (tid & 3) * 8;
  const int rb1 = ra + 64;

  for (int k0 = 0; k0 < 1024; k0 += 32) {
    __builtin_amdgcn_global_load_lds(
        (const __attribute__((address_space(1))) void*)(A + (size_t)(row0 + ra) * 1024 + k0 + ca),
        (__attribute__((address_space(3))) void*)(As + tid * 8), 16, 0, 0);
    __builtin_amdgcn_global_load_lds(
        (const __attribute__((address_space(1))) void*)(Bt + (size_t)ra * 1024 + k0 + ca),
        (__attribute__((address_space(3))) void*)(Bs + tid * 8), 16, 0, 0);
    __builtin_amdgcn_global_load_lds(
        (const __attribute__((address_space(1))) void*)(Bt + (size_t)rb1 * 1024 + k0 + ca),
        (__attribute__((address_space(3))) void*)(Bs + (tid + 256) * 8), 16, 0, 0);
    __syncthreads();
    bf16x8 af[4], bf[2];
#pragma unroll
    for (int i = 0; i < 4; i++)
      af[i] = *(const bf16x8*)(As + ((i * 16 + fr) * 32 + fq * 8));
#pragma unroll
    for (int j = 0; j < 2; j++)
      bf[j] = *(const bf16x8*)(Bs + ((wc + j * 16 + fr) * 32 + fq * 8));
#pragma unroll
    for (int i = 0; i < 4; i++)
#pragma unroll
      for (int j = 0; j < 2; j++)
        acc[i][j] = __builtin_amdgcn_mfma_f32_16x16x32_bf16(af[i], bf[j], acc[i][j], 0, 0, 0);
    __syncthreads();
  }
#pragma unroll
  for (int i = 0; i < 4; i++) {
    int grow = row0 + i * 16 + fq * 4;
#pragma unroll
    for (int j = 0; j < 2; j++) {
      int gcol = wc + j * 16 + fr;
#pragma unroll
      for (int r = 0; r < 4; r++)
        Cb[(size_t)(grow + r) * 128 + gcol] = f2b(tanhf(acc[i][j][r]));
    }
  }
}

// ---------------------------------------------------------------------------
// Deep-pipelined bf16 GEMM (R1 version — best measured): M=8192, N=1024, K=1024.
// BM=128 x BN=256 x BK=64, 512 threads (8 waves, 64x64 wave tiles).
// 3 LDS buffers (144 KB dynamic), depth-2 prefetch, counted vmcnt(6)
// (never 0 in main loop), raw s_barrier (1 per K-tile), XOR chunk-swizzle
// both-sides, bijective XCD swizzle. grid (4, 64, gz); nwg % 8 == 0.
// ---------------------------------------------------------------------------
#define DP_ABUF 8192    /* u16: 128*64 */
#define DP_BBUF 16384   /* u16: 256*64 */
#define DP_SBUF 24576   /* u16 per buffer (48 KB) */
#define DP_SMEM_BYTES 147456 /* 3 buffers */

template <bool TRIPLE, bool F32OUT>
__global__ __launch_bounds__(512, 2) void gemm_dp(
    const u16* __restrict__ A0, const u16* __restrict__ A1,
    const u16* __restrict__ A2, const u16* __restrict__ B0,
    const u16* __restrict__ B1, const u16* __restrict__ B2,
    float* __restrict__ Cf, u16* __restrict__ C0, u16* __restrict__ C1,
    u16* __restrict__ C2) {
  extern __shared__ __align__(16) u16 smem[];
  // T1: bijective XCD swizzle over flattened grid (x fastest; gridDim=(4,64,z))
  const int nwg = (int)(gridDim.x * gridDim.y * gridDim.z);
  const int wg = (int)(blockIdx.x + (blockIdx.y << 2) + (blockIdx.z << 8));
  const int cpx = nwg >> 3;
  const int swz = (wg & 7) * cpx + (wg >> 3);
  const int bx = swz & 3;
  const int by = (swz >> 2) & 63;
  const int bz = swz >> 8;

  const u16* __restrict__ A;
  const u16* __restrict__ Bt;
  u16* __restrict__ Cb;
  if (TRIPLE) {
    switch (bz) {
      case 0: A = A0; Bt = B0; Cb = C0; break;
      case 1: A = A1; Bt = B1; Cb = C1; break;
      default: A = A2; Bt = B2; Cb = C2; break;
    }
  } else {
    A = A0; Bt = B0; Cb = C0;
  }

  const int tid = threadIdx.x;
  const int lane = tid & 63;
  const int wave = tid >> 6;        // 0..7
  const int wr = (wave >> 2) * 64;  // 0 / 64
  const int wc = (wave & 3) * 64;   // 0 / 64 / 128 / 192
  const int fr = lane & 15;
  const int fq = lane >> 4;
  const int s8 = fr & 7;            // == (frag row) & 7
  const int row0 = by * 128;
  const int col0 = bx * 256;

  // per-lane LDS frag offsets (u16 units), loop-invariant
  int aoff[4][2], boff[4][2];
#pragma unroll
  for (int mi = 0; mi < 4; mi++)
#pragma unroll
    for (int ks = 0; ks < 2; ks++)
      aoff[mi][ks] = (wr + mi * 16 + fr) * 64 + (((ks * 4 + fq) ^ s8) * 8);
#pragma unroll
  for (int nj = 0; nj < 4; nj++)
#pragma unroll
    for (int ks = 0; ks < 2; ks++)
      boff[nj][ks] = (wc + nj * 16 + fr) * 64 + (((ks * 4 + fq) ^ s8) * 8);

  // stage tile kt (6 x 16B per thread) into buffer q; global source is
  // pre-swizzled so linear LDS dest + swizzled read = consistent involution.
  auto stage = [&](int kt, int q) {
    const u16* __restrict__ gA = A + (size_t)row0 * 1024 + kt * 64;
    const u16* __restrict__ gB = Bt + (size_t)col0 * 1024 + kt * 64;
    u16* dA = smem + q * DP_SBUF;
    u16* dB = dA + DP_ABUF;
#pragma unroll
    for (int p = 0; p < 2; p++) {
      int pos = tid + p * 512;          // 0..1023
      int r = pos >> 3, gch = (pos & 7) ^ (r & 7);
      __builtin_amdgcn_global_load_lds(
          (const __attribute__((address_space(1))) void*)(gA + (size_t)r * 1024 + gch * 8),
          (__attribute__((address_space(3))) void*)(dA + pos * 8), 16, 0, 0);
    }
#pragma unroll
    for (int p = 0; p < 4; p++) {
      int pos = tid + p * 512;          // 0..2047
      int r = pos >> 3, gch = (pos & 7) ^ (r & 7);
      __builtin_amdgcn_global_load_lds(
          (const __attribute__((address_space(1))) void*)(gB + (size_t)r * 1024 + gch * 8),
          (__attribute__((address_space(3))) void*)(dB + pos * 8), 16, 0, 0);
    }
  };

  f32x4 acc[4][4];
#pragma unroll
  for (int mi = 0; mi < 4; mi++)
#pragma unroll
    for (int nj = 0; nj < 4; nj++) acc[mi][nj] = (f32x4){0.f, 0.f, 0.f, 0.f};

  auto iter_body = [&](int qc, int qs, bool dostage, int t2) {
    if (dostage) stage(t2, qs);  // issue next+1 tile loads early
    const u16* sA = smem + qc * DP_SBUF;
    const u16* sB = sA + DP_ABUF;
    bf16x8 av[4][2], bv[4][2];
#pragma unroll
    for (int mi = 0; mi < 4; mi++)
#pragma unroll
      for (int ks = 0; ks < 2; ks++)
        av[mi][ks] = *(const bf16x8*)(sA + aoff[mi][ks]);
#pragma unroll
    for (int nj = 0; nj < 4; nj++)
#pragma unroll
      for (int ks = 0; ks < 2; ks++)
        bv[nj][ks] = *(const bf16x8*)(sB + boff[nj][ks]);
    __builtin_amdgcn_s_setprio(1);
#pragma unroll
    for (int ks = 0; ks < 2; ks++)
#pragma unroll
      for (int mi = 0; mi < 4; mi++)
#pragma unroll
        for (int nj = 0; nj < 4; nj++)
          acc[mi][nj] = __builtin_amdgcn_mfma_f32_16x16x32_bf16(
              av[mi][ks], bv[nj][ks], acc[mi][nj], 0, 0, 0);
    __builtin_amdgcn_s_setprio(0);
  };

  // prologue: 2 tiles in flight (12 loads)
  stage(0, 0);
  stage(1, 1);
  int qc = 0, qs = 2;
  // main loop: wait current tile (vmcnt 6: leaves next tile's 6 in flight)
  for (int t = 0; t < 14; t++) {
    asm volatile("s_waitcnt vmcnt(6)" ::: "memory");
    __builtin_amdgcn_s_barrier();
    iter_body(qc, qs, true, t + 2);
    qc = (qc == 2) ? 0 : qc + 1;
    qs = (qs == 2) ? 0 : qs + 1;
  }
  // t = 14: no more staging; tile 15's 6 loads remain in flight
  asm volatile("s_waitcnt vmcnt(6)" ::: "memory");
  __builtin_amdgcn_s_barrier();
  iter_body(qc, 0, false, 0);
  qc = (qc == 2) ? 0 : qc + 1;
  // t = 15: drain
  asm volatile("s_waitcnt vmcnt(0)" ::: "memory");
  __builtin_amdgcn_s_barrier();
  iter_body(qc, 0, false, 0);

#pragma unroll
  for (int mi = 0; mi < 4; mi++) {
    int grow = row0 + wr + mi * 16 + fq * 4;
#pragma unroll
    for (int nj = 0; nj < 4; nj++) {
      int gcol = col0 + wc + nj * 16 + fr;
#pragma unroll
      for (int r = 0; r < 4; r++) {
        if (F32OUT)
          Cf[(size_t)(grow + r) * 1024 + gcol] = acc[mi][nj][r];
        else
          Cb[(size_t)(grow + r) * 1024 + gcol] = f2b(acc[mi][nj][r]);
      }
    }
  }
}

// ---------------------------------------------------------------------------
// 3. blend via MFMA (fused x/xx/tm* epilogue); xx recomputed inline from x.
// ---------------------------------------------------------------------------
__global__ __launch_bounds__(256) void blend_mfma(
    const u16* __restrict__ mb, const u16* __restrict__ w2T,
    const float* __restrict__ x,
    const float* __restrict__ tmw, const float* __restrict__ tmk,
    const float* __restrict__ tmv, const float* __restrict__ tmr,
    u16* __restrict__ xwb, u16* __restrict__ xkb, u16* __restrict__ xvb,
    u16* __restrict__ xrb) {
  __shared__ u16 mS[64 * 136];
  __shared__ u16 wS[64 * 136];
  const int tid = threadIdx.x;
  const int lane = tid & 63;
  const int w = tid >> 6;
  const int fr = lane & 15;
  const int fq = lane >> 4;
  const int c0 = blockIdx.x * 64;
  const int bt0 = blockIdx.y * 64;

#pragma unroll
  for (int it = 0; it < 4; it++) {
    int idx = tid + it * 256;  // 0..1023
    int r = idx >> 4, c8 = (idx & 15) * 8;
    bf16x8 v = *(const bf16x8*)(mb + (size_t)(bt0 + r) * 128 + c8);
    *(bf16x4*)(mS + r * 136 + c8) = __builtin_shufflevector(v, v, 0, 1, 2, 3);
    *(bf16x4*)(mS + r * 136 + c8 + 4) = __builtin_shufflevector(v, v, 4, 5, 6, 7);
    bf16x8 u = *(const bf16x8*)(w2T + (size_t)(c0 + r) * 128 + c8);
    *(bf16x4*)(wS + r * 136 + c8) = __builtin_shufflevector(u, u, 0, 1, 2, 3);
    *(bf16x4*)(wS + r * 136 + c8 + 4) = __builtin_shufflevector(u, u, 4, 5, 6, 7);
  }
  __syncthreads();

  f32x4 acc[4][4];  // [col-tile j][f]
#pragma unroll
  for (int j = 0; j < 4; j++)
#pragma unroll
    for (int f = 0; f < 4; f++) acc[j][f] = (f32x4){0.f, 0.f, 0.f, 0.f};

#pragma unroll
  for (int f = 0; f < 4; f++) {
    bf16x8 aA = ldfrag(mS + (w * 16 + fr) * 136 + f * 32 + fq * 8);
#pragma unroll
    for (int j = 0; j < 4; j++) {
      bf16x8 bB = ldfrag(wS + (j * 16 + fr) * 136 + f * 32 + fq * 8);
      acc[j][f] = __builtin_amdgcn_mfma_f32_16x16x32_bf16(aA, bB, acc[j][f], 0, 0, 0);
    }
  }

#pragma unroll
  for (int j = 0; j < 4; j++) {
    int c = c0 + j * 16 + fr;
    float w_ = tmw[c], k_ = tmk[c], v_ = tmv[c], r_ = tmr[c];
#pragma unroll
    for (int rr = 0; rr < 4; rr++) {
      int bt = bt0 + w * 16 + fq * 4 + rr;
      size_t g = (size_t)bt * 1024 + c;
      float xv_ = x[g];
      float xp = ((bt & 2047) != 0) ? x[g - 1024] : 0.f;
      float dx = xp - xv_;
      xwb[g] = f2b(xv_ + dx * (w_ + acc[j][0][rr]));
      xkb[g] = f2b(xv_ + dx * (k_ + acc[j][1][rr]));
      xvb[g] = f2b(xv_ + dx * (v_ + acc[j][2][rr]));
      xrb[g] = f2b(xv_ + dx * (r_ + acc[j][3][rr]));
    }
  }
}

// ---------------------------------------------------------------------------
// 5a. decay reduce: dw2r f32 [64][16], tdr f32 [16], dw2rbT bf16 [16][64]
// ---------------------------------------------------------------------------
__global__ __launch_bounds__(256) void dw2r_kernel(const float* __restrict__ dw2,
                                                   const float* __restrict__ td,
                                                   float* __restrict__ dw2r,
                                                   float* __restrict__ tdr,
                                                   u16* __restrict__ dw2rbT) {
  int idx = blockIdx.x * 256 + threadIdx.x;
  if (idx < 1024) {
    int j = idx >> 4, h = idx & 15;
    float s = 0.f;
    for (int n = 0; n < 64; n++) s += dw2[(size_t)j * 1024 + h * 64 + n];
    float m = s * (1.f / 64.f);
    dw2r[j * 16 + h] = m;
    dw2rbT[h * 64 + j] = f2b(m);
  }
  if (idx < 16) {
    float s = 0.f;
    for (int n = 0; n < 64; n++) s += td[idx * 64 + n];
    tdr[idx] = s * (1.f / 64.f);
  }
}

// ---------------------------------------------------------------------------
// 5b. fused decay GEMM: h1 = tanh(xw @ d1) via MFMA (K=1024), then
//     wlog = -exp(tdr + h1 @ dw2r) via a second 2-step MFMA. 64-row tiles.
// ---------------------------------------------------------------------------
__global__ __launch_bounds__(256) void decay_mfma(const u16* __restrict__ xwb,
                                                  const u16* __restrict__ d1T,
                                                  const u16* __restrict__ dw2rbT,
                                                  const float* __restrict__ tdr,
                                                  float* __restrict__ wlog) {
  __shared__ u16 As[64 * 32];
  __shared__ u16 Bs[64 * 32];
  __shared__ u16 h1S[64 * 72];
  __shared__ u16 dwS[16 * 72];
  const int tid = threadIdx.x;
  const int lane = tid & 63;
  const int w = tid >> 6;
  const int fr = lane & 15;
  const int fq = lane >> 4;
  const int bt0 = blockIdx.x * 64;

#pragma unroll
  for (int it = 0; it < 4; it++) {
    int idx = tid + it * 256;
    int r = idx >> 6, c = idx & 63;
    dwS[r * 72 + c] = dw2rbT[r * 64 + c];
  }

  f32x4 acc[4];
#pragma unroll
  for (int j = 0; j < 4; j++) acc[j] = (f32x4){0.f, 0.f, 0.f, 0.f};

  const int ra = tid >> 2, ca = (tid & 3) * 8;
  for (int k0 = 0; k0 < 1024; k0 += 32) {
    __builtin_amdgcn_global_load_lds(
        (const __attribute__((address_space(1))) void*)(xwb + (size_t)(bt0 + ra) * 1024 + k0 + ca),
        (__attribute__((address_space(3))) void*)(As + tid * 8), 16, 0, 0);
    __builtin_amdgcn_global_load_lds(
        (const __attribute__((address_space(1))) void*)(d1T + (size_t)ra * 1024 + k0 + ca),
        (__attribute__((address_space(3))) void*)(Bs + tid * 8), 16, 0, 0);
    __syncthreads();
    bf16x8 aA = *(const bf16x8*)(As + ((w * 16 + fr) * 32 + fq * 8));
#pragma unroll
    for (int j = 0; j < 4; j++) {
      bf16x8 bB = *(const bf16x8*)(Bs + ((j * 16 + fr) * 32 + fq * 8));
      acc[j] = __builtin_amdgcn_mfma_f32_16x16x32_bf16(aA, bB, acc[j], 0, 0, 0);
    }
    __syncthreads();
  }
#pragma unroll
  for (int j = 0; j < 4; j++)
#pragma unroll
    for (int rr = 0; rr < 4; rr++)
      h1S[(w * 16 + fq * 4 + rr) * 72 + j * 16 + fr] = f2b(tanhf(acc[j][rr]));
  __syncthreads();

  f32x4 a2 = (f32x4){0.f, 0.f, 0.f, 0.f};
#pragma unroll
  for (int ks = 0; ks < 2; ks++) {
    bf16x8 aA = ldfrag(h1S + (w * 16 + fr) * 72 + ks * 32 + fq * 8);
    bf16x8 bB = ldfrag(dwS + fr * 72 + ks * 32 + fq * 8);
    a2 = __builtin_amdgcn_mfma_f32_16x16x32_bf16(aA, bB, a2, 0, 0, 0);
  }
  float tdv = tdr[fr];
#pragma unroll
  for (int rr = 0; rr < 4; rr++) {
    int bt = bt0 + w * 16 + fq * 4 + rr;
    int b = bt >> 11, tl = bt & 2047;
    wlog[((size_t)(b * 16 + fr)) * 2048 + tl] = -__expf(tdv + a2[rr]);
  }
}

// ---------------------------------------------------------------------------
// 7. per-chunk scan
// ---------------------------------------------------------------------------
__global__ __launch_bounds__(256) void wprep_kernel(const float* __restrict__ wlog,
                                                    float* __restrict__ cum,
                                                    float* __restrict__ excl,
                                                    float* __restrict__ wsl) {
  int bid = blockIdx.x;
  int c = bid & 7, bh = bid >> 3;
  int q = threadIdx.x;
  float v = wlog[(size_t)bh * 2048 + c * 256 + q];
  __shared__ float s[256];
  s[q] = v;
  float val = v;
  for (int off = 1; off < 256; off <<= 1) {
    __syncthreads();
    float t = (q >= off) ? s[q - off] : 0.f;
    __syncthreads();
    val += t;
    s[q] = val;
  }
  __syncthreads();
  float total = s[255];
  cum[(size_t)bid * 256 + q] = val;
  excl[(size_t)bid * 256 + q] = val - v;
  if (q == 0) wsl[bid] = total;
}

// ---------------------------------------------------------------------------
// kvtrans2: per-head transpose of bf16 k,v (k scaled by w_inter on output),
// plus diag[b,h,t] = sum_n r*fa*k (raw k), via full-wave reduce.
// ---------------------------------------------------------------------------
__global__ __launch_bounds__(256) void kvtrans2_kernel(
    const u16* __restrict__ vb, const u16* __restrict__ kb,
    const u16* __restrict__ rb, const float* __restrict__ faaaa,
    const float* __restrict__ cum, const float* __restrict__ wsl,
    u16* __restrict__ vT, u16* __restrict__ kTw, float* __restrict__ diagG) {
  int tt = blockIdx.x;  // t-tile 0..31
  int bh = blockIdx.y;  // 0..63
  int b = bh >> 4, h = bh & 15;
  int cc = tt >> 2;
  int bidc = bh * 8 + cc;
  __shared__ float tv[64][65];
  __shared__ float tk[64][65];
  __shared__ float wfac[64];
  __shared__ float faS[64];
  const int tid = threadIdx.x;
  float wslog = wsl[bidc];
  if (tid < 64) {
    wfac[tid] = __expf(wslog - cum[(size_t)bidc * 256 + (tt & 3) * 64 + tid]);
    faS[tid] = faaaa[h * 64 + tid];
  }
  __syncthreads();
  const int m = tid & 63;
  float fam = faS[m];
#pragma unroll
  for (int it = 0; it < 16; it++) {
    int r = it * 4 + (tid >> 6);
    size_t g = ((size_t)(b * TT + tt * 64 + r)) * CC + h * 64 + m;
    float vraw = b2f(vb[g]);
    float kraw = b2f(kb[g]);
    float rraw = b2f(rb[g]);
    tv[r][m] = vraw;
    tk[r][m] = kraw;
    float s = rraw * fam * kraw;
    s += __shfl_xor(s, 1);
    s += __shfl_xor(s, 2);
    s += __shfl_xor(s, 4);
    s += __shfl_xor(s, 8);
    s += __shfl_xor(s, 16);
    s += __shfl_xor(s, 32);
    if (m == 0) diagG[(size_t)bh * 2048 + tt * 64 + r] = s;
  }
  __syncthreads();
#pragma unroll
  for (int it = 0; it < 16; it++) {
    int idx = it * 256 + tid;
    int mm = idx >> 6, tl = idx & 63;
    size_t o = ((size_t)(bh * 64 + mm)) * TT + tt * 64 + tl;
    vT[o] = f2b(tv[tl][mm]);
    kTw[o] = f2b(tk[tl][mm] * wfac[tl]);
  }
}

// ---------------------------------------------------------------------------
// 8a. kv via MFMA
// ---------------------------------------------------------------------------
__global__ __launch_bounds__(256) void kv_mfma(const u16* __restrict__ kTw,
                                               const u16* __restrict__ vT,
                                               float* __restrict__ kvb) {
  int bid = blockIdx.x;
  int c = bid & 7, bh = bid >> 3;
  __shared__ u16 kS[64 * 72];
  __shared__ u16 vS[64 * 72];
  const int tid = threadIdx.x;
  const int lane = tid & 63;
  const int w = tid >> 6;
  const int fr = lane & 15;
  const int fq = lane >> 4;
  f32x4 acc[4];
#pragma unroll
  for (int j = 0; j < 4; j++) acc[j] = (f32x4){0.f, 0.f, 0.f, 0.f};
  const size_t base = (size_t)bh * 64 * TT + c * QQ;
  for (int qt = 0; qt < 4; qt++) {
    __syncthreads();
    stage_tile(kTw, base + qt * 64, TT, tid, kS);
    stage_tile(vT, base + qt * 64, TT, tid, vS);
    __syncthreads();
#pragma unroll
    for (int ks = 0; ks < 2; ks++) {
      bf16x8 aA = ldfrag(kS + (w * 16 + fr) * 72 + ks * 32 + fq * 8);
#pragma unroll
      for (int j = 0; j < 4; j++) {
        bf16x8 bB = ldfrag(vS + (j * 16 + fr) * 72 + ks * 32 + fq * 8);
        acc[j] = __builtin_amdgcn_mfma_f32_16x16x32_bf16(aA, bB, acc[j], 0, 0, 0);
      }
    }
  }
#pragma unroll
  for (int j = 0; j < 4; j++)
#pragma unroll
    for (int rr = 0; rr < 4; rr++)
      kvb[(size_t)bid * 4096 + (w * 16 + fq * 4 + rr) * 64 + j * 16 + fr] = acc[j][rr];
}

// ---------------------------------------------------------------------------
// 8b. sequential state scan over chunks — 256 blocks (bh x 4 slices)
// ---------------------------------------------------------------------------
__global__ __launch_bounds__(256) void scan_kernel(const float* __restrict__ kvb,
                                                   const float* __restrict__ wsl,
                                                   float* __restrict__ st) {
  int bh = blockIdx.x >> 2;
  int sl = blockIdx.x & 3;
  int tid = threadIdx.x;
  float s[4];
#pragma unroll
  for (int i = 0; i < 4; i++) s[i] = 0.f;
  for (int c = 0; c < 8; c++) {
    int bid = bh * 8 + c;
    float w = __expf(wsl[bid]);
#pragma unroll
    for (int i = 0; i < 4; i++) {
      size_t e = (size_t)bid * 4096 + sl * 1024 + i * 256 + tid;
      st[e] = s[i];
      s[i] = w * s[i] + kvb[e];
    }
  }
}

// ---------------------------------------------------------------------------
// 9. MFMA fused attention. Mask via factored exp tables:
// exp(excl[q]-cum[k]) = exp(excl[q]-cc) * exp(cc-cum[k]), cc = cum[127]
// (both exponents bounded ~|47| -> no overflow; true product <= 1).
// Diagonal read from diagG (precomputed in kvtrans2).
// ---------------------------------------------------------------------------
__global__ __launch_bounds__(256) void attn_mfma(
    const u16* __restrict__ rb, const u16* __restrict__ kb,
    const u16* __restrict__ vT, const float* __restrict__ stg,
    const float* __restrict__ cum, const float* __restrict__ excl,
    const float* __restrict__ diagG, float* __restrict__ y) {
  int bid = blockIdx.x;
  int c = bid & 7, bh = bid >> 3;
  int b = bh >> 4, h = bh & 15;
  __shared__ u16 rt[64 * 72];
  __shared__ u16 kt[64 * 72];
  __shared__ u16 vt[64 * 72];
  __shared__ u16 pt[64 * 72];
  __shared__ u16 stT[64 * 72];
  __shared__ float cumS[256], exS[256], diagS[256], ekS[256];

  const int tid = threadIdx.x;
  const int lane = tid & 63;
  const int w = tid >> 6;
  const int fr = lane & 15;
  const int fq = lane >> 4;

  cumS[tid] = cum[(size_t)bid * 256 + tid];
  exS[tid] = excl[(size_t)bid * 256 + tid];
  diagS[tid] = diagG[(size_t)bh * 2048 + c * 256 + tid];
#pragma unroll
  for (int it = 0; it < 16; it++) {
    int idx = tid + it * 256;
    int n = idx >> 6, mm = idx & 63;
    stT[mm * 72 + n] = f2b(stg[(size_t)bid * 4096 + idx]);
  }
  __syncthreads();
  const float ccm = cumS[127];
  ekS[tid] = __expf(ccm - cumS[tid]);

  const size_t rowbase = ((size_t)b * TT + c * QQ) * CC + h * 64;
  const size_t vbase0 = (size_t)bh * 64 * TT + c * QQ;

  for (int qt = 0; qt < 4; qt++) {
    __syncthreads();
    stage_tile(rb, rowbase + (size_t)(qt * 64) * CC, CC, tid, rt);
    __syncthreads();

    f32x4 acc[4];
#pragma unroll
    for (int jm = 0; jm < 4; jm++) acc[jm] = (f32x4){0.f, 0.f, 0.f, 0.f};
    bf16x8 rA[2];
    rA[0] = ldfrag(rt + (w * 16 + fr) * 72 + fq * 8);
    rA[1] = ldfrag(rt + (w * 16 + fr) * 72 + 32 + fq * 8);
#pragma unroll
    for (int ks = 0; ks < 2; ks++)
#pragma unroll
      for (int jm = 0; jm < 4; jm++) {
        bf16x8 bB = ldfrag(stT + (jm * 16 + fr) * 72 + ks * 32 + fq * 8);
        acc[jm] = __builtin_amdgcn_mfma_f32_16x16x32_bf16(rA[ks], bB, acc[jm], 0, 0, 0);
      }
    int ql0 = w * 16 + fq * 4;
    float er[4], eqc[4];
#pragma unroll
    for (int rr = 0; rr < 4; rr++) {
      float ex = exS[qt * 64 + ql0 + rr];
      er[rr] = __expf(ex);
      eqc[rr] = __expf(ex - ccm);
    }
#pragma unroll
    for (int jm = 0; jm < 4; jm++)
#pragma unroll
      for (int rr = 0; rr < 4; rr++) acc[jm][rr] *= er[rr];

    for (int kti = 0; kti <= qt; kti++) {
      __syncthreads();
      stage_tile(kb, rowbase + (size_t)(kti * 64) * CC, CC, tid, kt);
      stage_tile(vT, vbase0 + (size_t)(kti * 64), TT, tid, vt);
      __syncthreads();

      f32x4 sacc[4];
#pragma unroll
      for (int jj = 0; jj < 4; jj++) sacc[jj] = (f32x4){0.f, 0.f, 0.f, 0.f};
#pragma unroll
      for (int ks = 0; ks < 2; ks++)
#pragma unroll
        for (int jj = 0; jj < 4; jj++) {
          bf16x8 bB = ldfrag(kt + (jj * 16 + fr) * 72 + ks * 32 + fq * 8);
          sacc[jj] = __builtin_amdgcn_mfma_f32_16x16x32_bf16(rA[ks], bB, sacc[jj], 0, 0, 0);
        }
#pragma unroll
      for (int jj = 0; jj < 4; jj++) {
        int kcol = kti * 64 + jj * 16 + fr;
        float ek = ekS[kcol];
#pragma unroll
        for (int rr = 0; rr < 4; rr++) {
          int qrow = qt * 64 + ql0 + rr;
          float vsc;
          if (kcol < qrow)
            vsc = sacc[jj][rr] * eqc[rr] * ek;
          else if (kcol == qrow)
            vsc = diagS[qrow];
          else
            vsc = 0.f;
          pt[(ql0 + rr) * 72 + jj * 16 + fr] = f2b(vsc);
        }
      }
      __syncthreads();
#pragma unroll
      for (int ks = 0; ks < 2; ks++) {
        bf16x8 pA = ldfrag(pt + (w * 16 + fr) * 72 + ks * 32 + fq * 8);
#pragma unroll
        for (int jm = 0; jm < 4; jm++) {
          bf16x8 vB = ldfrag(vt + (jm * 16 + fr) * 72 + ks * 32 + fq * 8);
          acc[jm] = __builtin_amdgcn_mfma_f32_16x16x32_bf16(pA, vB, acc[jm], 0, 0, 0);
        }
      }
    }
    int qg0 = qt * 64 + w * 16 + fq * 4;
#pragma unroll
    for (int jm = 0; jm < 4; jm++)
#pragma unroll
      for (int rr = 0; rr < 4; rr++)
        y[rowbase + (size_t)(qg0 + rr) * CC + jm * 16 + fr] = acc[jm][rr];
  }
}

// ---------------------------------------------------------------------------
// 10. LayerNorm over C -> bf16
// ---------------------------------------------------------------------------
__global__ __launch_bounds__(256) void ln_kernel(const float* __restrict__ y,
                                                 const float* __restrict__ g,
                                                 const float* __restrict__ bta,
                                                 u16* __restrict__ out) {
  __shared__ float red[8];
  int bt = blockIdx.x;
  int tid = threadIdx.x;
  float v[4];
  float s = 0.f;
#pragma unroll
  for (int i = 0; i < 4; i++) {
    v[i] = y[(size_t)bt * 1024 + i * 256 + tid];
    s += v[i];
  }
#pragma unroll
  for (int off = 32; off > 0; off >>= 1) s += __shfl_down(s, off);
  if ((tid & 63) == 0) red[tid >> 6] = s;
  __syncthreads();
  if (tid == 0) red[4] = red[0] + red[1] + red[2] + red[3];
  __syncthreads();
  float mu = red[4] * (1.f / 1024.f);
  float s2 = 0.f;
#pragma unroll
  for (int i = 0; i < 4; i++) {
    float d = v[i] - mu;
    s2 += d * d;
  }
#pragma unroll
  for (int off = 32; off > 0; off >>= 1) s2 += __shfl_down(s2, off);
  __syncthreads();
  if ((tid & 63) == 0) red[tid >> 6] = s2;
  __syncthreads();
  if (tid == 0) red[5] = red[0] + red[1] + red[2] + red[3];
  __syncthreads();
  float var = red[5] * (1.f / 1024.f);
  float rstd = rsqrtf(var + 1e-5f);
#pragma unroll
  for (int i = 0; i < 4; i++) {
    int c = i * 256 + tid;
    out[(size_t)bt * 1024 + c] = f2b((v[i] - mu) * rstd * g[c] + bta[c]);
  }
}

// ---------------------------------------------------------------------------
extern "C" void kernel_launch(void* const* d_in, const int* in_sizes, int n_in,
                              void* d_out, int out_size, void* d_ws,
                              size_t ws_size, hipStream_t stream) {
  const float* x = (const float*)d_in[0];
  const float* tmx = (const float*)d_in[1];
  const float* tmw = (const float*)d_in[2];
  const float* tmk = (const float*)d_in[3];
  const float* tmv = (const float*)d_in[4];
  const float* tmr = (const float*)d_in[5];
  const float* maa_w1 = (const float*)d_in[6];
  const float* maa_w2 = (const float*)d_in[7];
  const float* decay_w1 = (const float*)d_in[8];
  const float* decay_w2 = (const float*)d_in[9];
  const float* time_decay = (const float*)d_in[10];
  const float* faaaa = (const float*)d_in[11];
  const float* Wr = (const float*)d_in[12];
  const float* Wk = (const float*)d_in[13];
  const float* Wv = (const float*)d_in[14];
  const float* Wo = (const float*)d_in[15];
  const float* lng = (const float*)d_in[16];
  const float* lnb = (const float*)d_in[17];
  float* out = (float*)d_out;
  float* ws = (float*)d_ws;

  const size_t S = (size_t)BT * CC;  // 8388608

  // f32 region
  float* y_ = ws;                     // attn out (was the xx slot)
  float* dw2r = ws + S;               // 1024
  float* tdr = dw2r + 1024;           // pad to 1024
  float* wlog = tdr + 1024;           // 131072
  float* cum = wlog + 131072;
  float* excl = cum + 131072;
  float* wsl = excl + 131072;         // pad to 1024
  float* diagG = wsl + 1024;          // 131072
  float* kvb = diagG + 131072;        // 512*4096
  float* stb = kvb + (size_t)512 * 4096;
  float* fend = stb + (size_t)512 * 4096;
  // bf16 region (u16)
  u16* xxxb = (u16*)fend;             // mix out -> maa GEMM in -> vT
  u16* mb = xxxb + S;                 // BT*128
  u16* xkb = mb + (size_t)BT * 128;   // blend out -> gemm_dp in -> ylnb
  u16* xvb = xkb + S;                 // blend out -> gemm_dp in
  u16* xrb = xvb + S;                 // blend out -> gemm_dp in -> kTw
  u16* xwb = xrb + S;                 // blend out -> decay_mfma in
  u16* rb16 = xwb + S;                // gemm_dp out
  u16* kb16 = rb16 + S;               // gemm_dp out
  u16* Vb = kb16 + S;                 // gemm_dp out
  u16* Wrt = Vb + S;
  u16* Wkt = Wrt + (size_t)1024 * 1024;
  u16* Wvt = Wkt + (size_t)1024 * 1024;
  u16* Wot = Wvt + (size_t)1024 * 1024;
  u16* w1T = Wot + (size_t)1024 * 1024;   // [128][1024]
  u16* w2T = w1T + (size_t)128 * 1024;    // [1024][128]
  u16* d1T = w2T + (size_t)1024 * 128;    // [64][1024]
  u16* dw2rbT = d1T + (size_t)64 * 1024;  // [16][64]
  // aliases (stream-ordered reuse)
  u16* vT = xxxb;   // after maa GEMM consumed xxxb
  u16* kTw = xrb;   // after gemm_dp consumed xrb
  u16* ylnb = xkb;  // after gemm_dp consumed xkb

  // allow 144 KB dynamic LDS for the deep-pipelined GEMMs (once per process)
  static bool attr_done = false;
  if (!attr_done) {
    hipFuncSetAttribute((const void*)gemm_dp<true, false>,
                        hipFuncAttributeMaxDynamicSharedMemorySize, DP_SMEM_BYTES);
    hipFuncSetAttribute((const void*)gemm_dp<false, true>,
                        hipFuncAttributeMaxDynamicSharedMemorySize, DP_SMEM_BYTES);
    attr_done = true;
  }

  cvt_wT<<<dim3(16, 16, 4), 256, 0, stream>>>(Wr, Wk, Wv, Wo, Wrt, Wkt, Wvt, Wot);
  cvt3_T<<<dim3(16, 16, 3), 256, 0, stream>>>(maa_w1, maa_w2, decay_w1, w1T,
                                              w2T, d1T);
  dw2r_kernel<<<4, 256, 0, stream>>>(decay_w2, time_decay, dw2r, tdr, dw2rbT);
  mix_kernel<<<8192, 256, 0, stream>>>(x, tmx, xxxb);
  gemm_maa<<<128, 256, 0, stream>>>(xxxb, w1T, mb);
  blend_mfma<<<dim3(16, 128), 256, 0, stream>>>(mb, w2T, x, tmw, tmk, tmv, tmr,
                                                xwb, xkb, xvb, xrb);
  decay_mfma<<<128, 256, 0, stream>>>(xwb, d1T, dw2rbT, tdr, wlog);
  wprep_kernel<<<512, 256, 0, stream>>>(wlog, cum, excl, wsl);
  // fused r/k/v projections: deep-pipelined GEMM (R1 structure)
  gemm_dp<true, false><<<dim3(4, 64, 3), 512, DP_SMEM_BYTES, stream>>>(
      xrb, xkb, xvb, Wrt, Wkt, Wvt, nullptr, rb16, kb16, Vb);
  kvtrans2_kernel<<<dim3(32, 64), 256, 0, stream>>>(Vb, kb16, rb16, faaaa, cum,
                                                    wsl, vT, kTw, diagG);
  kv_mfma<<<512, 256, 0, stream>>>(kTw, vT, kvb);
  scan_kernel<<<256, 256, 0, stream>>>(kvb, wsl, stb);
  attn_mfma<<<512, 256, 0, stream>>>(rb16, kb16, vT, stb, cum, excl, diagG, y_);
  ln_kernel<<<BT, 256, 0, stream>>>(y_, lng, lnb, ylnb);
  // output projection: same deep-pipelined GEMM, f32 out
  gemm_dp<false, true><<<dim3(4, 64, 1), 512, DP_SMEM_BYTES, stream>>>(
      ylnb, nullptr, nullptr, Wot, nullptr, nullptr, out, nullptr, nullptr,
      nullptr);
}

// Round 6
// 360.959 us; speedup vs baseline: 1.1723x; 1.0112x over previous
//
#include <hip/hip_runtime.h>
#include <math.h>

// B=4, T=2048, C=1024, H=16, N=64, Q=256, nc=8, BT=8192
#define BB 4
#define TT 2048
#define CC 1024
#define HH 16
#define NN 64
#define QQ 256
#define NCH 8
#define BT 8192

typedef unsigned short u16;
typedef __attribute__((ext_vector_type(8))) short bf16x8;
typedef __attribute__((ext_vector_type(4))) short bf16x4;
typedef __attribute__((ext_vector_type(4))) float f32x4;
typedef __attribute__((ext_vector_type(4))) u16 u16x4;

// f32 -> bf16 bits, round-to-nearest-even
__device__ inline u16 f2b(float x) {
  union { float f; unsigned u; } v;
  v.f = x;
  unsigned r = v.u + 0x7FFFu + ((v.u >> 16) & 1u);
  return (u16)(r >> 16);
}
__device__ inline float b2f(u16 u) {
  union { unsigned u; float f; } v;
  v.u = ((unsigned)u) << 16;
  return v.f;
}
// 16B fragment from padded LDS row via two 8B loads (conflict-friendly)
__device__ inline bf16x8 ldfrag(const u16* p) {
  bf16x4 lo = *(const bf16x4*)p;
  bf16x4 hi = *(const bf16x4*)(p + 4);
  return __builtin_shufflevector(lo, hi, 0, 1, 2, 3, 4, 5, 6, 7);
}
// stage 64x64 bf16 tile (global pitch `pitch` u16) into LDS stride-72
__device__ inline void stage_tile(const u16* __restrict__ g, size_t base,
                                  int pitch, int tid, u16* __restrict__ lds) {
#pragma unroll
  for (int it = 0; it < 2; it++) {
    int cidx = tid + it * 256;  // 0..511
    int r = cidx >> 3, c8 = (cidx & 7) * 8;
    bf16x8 v = *(const bf16x8*)(g + base + (size_t)r * pitch + c8);
    *(bf16x4*)(lds + r * 72 + c8) = __builtin_shufflevector(v, v, 0, 1, 2, 3);
    *(bf16x4*)(lds + r * 72 + c8 + 4) = __builtin_shufflevector(v, v, 4, 5, 6, 7);
  }
}

// ---------------------------------------------------------------------------
// 1. time-shift mix: xxx -> bf16 only (xx recomputed inline in blend)
// ---------------------------------------------------------------------------
__global__ __launch_bounds__(256) void mix_kernel(const float* __restrict__ x,
                                                  const float* __restrict__ tmx,
                                                  u16* __restrict__ xxxb) {
  size_t e = ((size_t)blockIdx.x * 256 + threadIdx.x) * 4;
  int c = (int)(e & 1023);
  size_t row = e >> 10;
  int t = (int)(row & 2047);
  float4 xv = *(const float4*)(x + e);
  float4 pv = make_float4(0.f, 0.f, 0.f, 0.f);
  if (t > 0) pv = *(const float4*)(x + e - 1024);
  float4 d = make_float4(pv.x - xv.x, pv.y - xv.y, pv.z - xv.z, pv.w - xv.w);
  u16x4 o;
  o.x = f2b(xv.x + d.x * tmx[c + 0]);
  o.y = f2b(xv.y + d.y * tmx[c + 1]);
  o.z = f2b(xv.z + d.z * tmx[c + 2]);
  o.w = f2b(xv.w + d.w * tmx[c + 3]);
  *(u16x4*)(xxxb + e) = o;
}

// ---------------------------------------------------------------------------
// weight f32[k][n] (1024x1024) -> bf16 transposed Wt[n][k]
// ---------------------------------------------------------------------------
__global__ __launch_bounds__(256) void cvt_wT(const float* __restrict__ W0,
                                              const float* __restrict__ W1,
                                              const float* __restrict__ W2,
                                              const float* __restrict__ W3,
                                              u16* __restrict__ O0,
                                              u16* __restrict__ O1,
                                              u16* __restrict__ O2,
                                              u16* __restrict__ O3) {
  const float* W;
  u16* O;
  switch (blockIdx.z) {
    case 0: W = W0; O = O0; break;
    case 1: W = W1; O = O1; break;
    case 2: W = W2; O = O2; break;
    default: W = W3; O = O3; break;
  }
  __shared__ float t[64][65];
  int bx = blockIdx.x * 64;
  int by = blockIdx.y * 64;
#pragma unroll
  for (int it = 0; it < 16; it++) {
    int idx = it * 256 + threadIdx.x;
    int r = idx >> 6, c = idx & 63;
    t[r][c] = W[(size_t)(by + r) * 1024 + bx + c];
  }
  __syncthreads();
#pragma unroll
  for (int it = 0; it < 16; it++) {
    int idx = it * 256 + threadIdx.x;
    int n = idx >> 6, k = idx & 63;
    O[(size_t)(bx + n) * 1024 + by + k] = f2b(t[k][n]);
  }
}

// ---------------------------------------------------------------------------
// merged transpose+cvt for the small weights + decay reduce (one launch):
//   z=0: maa_w1 f32[1024][128] -> w1T bf16[128][1024]
//   z=1: maa_w2 f32[128][1024] -> w2T bf16[1024][128]
//   z=2: decay_w1 f32[1024][64] -> d1T bf16[64][1024]
//   z=3: dw2r reduce (blocks x<4, y==0 only)
// grid (16,16,4); out-of-range tiles return immediately.
// ---------------------------------------------------------------------------
__global__ __launch_bounds__(256) void cvt3_T(const float* __restrict__ w1,
                                              const float* __restrict__ w2,
                                              const float* __restrict__ d1,
                                              u16* __restrict__ o1,
                                              u16* __restrict__ o2,
                                              u16* __restrict__ o3,
                                              const float* __restrict__ dw2,
                                              const float* __restrict__ td,
                                              float* __restrict__ dw2r,
                                              float* __restrict__ tdr,
                                              u16* __restrict__ dw2rbT) {
  if (blockIdx.z == 3) {
    if (blockIdx.y != 0 || blockIdx.x >= 4) return;
    int idx = blockIdx.x * 256 + threadIdx.x;
    if (idx < 1024) {
      int j = idx >> 4, h = idx & 15;
      float s = 0.f;
      for (int n = 0; n < 64; n++) s += dw2[(size_t)j * 1024 + h * 64 + n];
      float m = s * (1.f / 64.f);
      dw2r[j * 16 + h] = m;
      dw2rbT[h * 64 + j] = f2b(m);
    }
    if (idx < 16) {
      float s = 0.f;
      for (int n = 0; n < 64; n++) s += td[idx * 64 + n];
      tdr[idx] = s * (1.f / 64.f);
    }
    return;
  }
  const float* in;
  u16* out;
  int R, C;
  switch (blockIdx.z) {
    case 0: in = w1; out = o1; R = 1024; C = 128; break;
    case 1: in = w2; out = o2; R = 128; C = 1024; break;
    default: in = d1; out = o3; R = 1024; C = 64; break;
  }
  int c0 = blockIdx.x * 64, r0 = blockIdx.y * 64;
  if (c0 >= C || r0 >= R) return;
  __shared__ float t[64][65];
#pragma unroll
  for (int it = 0; it < 16; it++) {
    int idx = it * 256 + threadIdx.x;
    int r = idx >> 6, c = idx & 63;
    t[r][c] = in[(size_t)(r0 + r) * C + c0 + c];
  }
  __syncthreads();
#pragma unroll
  for (int it = 0; it < 16; it++) {
    int idx = it * 256 + threadIdx.x;
    int c = idx >> 6, r = idx & 63;
    out[(size_t)(c0 + c) * R + r0 + r] = f2b(t[r][c]);
  }
}

// ---------------------------------------------------------------------------
// maa GEMM: mb = tanh(xxx @ w1) : A[8192][1024] x w1T[128][1024] -> [8192][128]
// 64x64 tiles -> grid (2,128) = 256 blocks (full-CU coverage).
// 4 waves; wave w owns cols [w*16, w*16+16). m97-style K loop.
// ---------------------------------------------------------------------------
__global__ __launch_bounds__(256) void gemm_maa(const u16* __restrict__ A,
                                                const u16* __restrict__ Bt,
                                                u16* __restrict__ Cb) {
  __shared__ u16 As[64 * 32];
  __shared__ u16 Bs[64 * 32];
  const int tid = threadIdx.x;
  const int lane = tid & 63;
  const int wave = tid >> 6;
  const int wc = wave * 16;
  const int fr = lane & 15;
  const int fq = lane >> 4;
  const int row0 = blockIdx.y * 64;
  const int col0 = blockIdx.x * 64;

  f32x4 acc[4];
#pragma unroll
  for (int i = 0; i < 4; i++) acc[i] = (f32x4){0.f, 0.f, 0.f, 0.f};

  const int ra = tid >> 2, ca = (tid & 3) * 8;

  for (int k0 = 0; k0 < 1024; k0 += 32) {
    __builtin_amdgcn_global_load_lds(
        (const __attribute__((address_space(1))) void*)(A + (size_t)(row0 + ra) * 1024 + k0 + ca),
        (__attribute__((address_space(3))) void*)(As + tid * 8), 16, 0, 0);
    __builtin_amdgcn_global_load_lds(
        (const __attribute__((address_space(1))) void*)(Bt + (size_t)(col0 + ra) * 1024 + k0 + ca),
        (__attribute__((address_space(3))) void*)(Bs + tid * 8), 16, 0, 0);
    __syncthreads();
    bf16x8 bf = *(const bf16x8*)(Bs + ((wc + fr) * 32 + fq * 8));
#pragma unroll
    for (int i = 0; i < 4; i++) {
      bf16x8 af = *(const bf16x8*)(As + ((i * 16 + fr) * 32 + fq * 8));
      acc[i] = __builtin_amdgcn_mfma_f32_16x16x32_bf16(af, bf, acc[i], 0, 0, 0);
    }
    __syncthreads();
  }
#pragma unroll
  for (int i = 0; i < 4; i++) {
    int grow = row0 + i * 16 + fq * 4;
#pragma unroll
    for (int r = 0; r < 4; r++)
      Cb[(size_t)(grow + r) * 128 + col0 + wc + fr] = f2b(tanhf(acc[i][r]));
  }
}

// ---------------------------------------------------------------------------
// Deep-pipelined bf16 GEMM (R1 version — best measured): M=8192, N=1024, K=1024.
// BM=128 x BN=256 x BK=64, 512 threads (8 waves, 64x64 wave tiles).
// 3 LDS buffers (144 KB dynamic), depth-2 prefetch, counted vmcnt(6)
// (never 0 in main loop), raw s_barrier (1 per K-tile), XOR chunk-swizzle
// both-sides, bijective XCD swizzle. grid (4, 64, gz); nwg % 8 == 0.
// ---------------------------------------------------------------------------
#define DP_ABUF 8192    /* u16: 128*64 */
#define DP_BBUF 16384   /* u16: 256*64 */
#define DP_SBUF 24576   /* u16 per buffer (48 KB) */
#define DP_SMEM_BYTES 147456 /* 3 buffers */

template <bool TRIPLE, bool F32OUT>
__global__ __launch_bounds__(512, 2) void gemm_dp(
    const u16* __restrict__ A0, const u16* __restrict__ A1,
    const u16* __restrict__ A2, const u16* __restrict__ B0,
    const u16* __restrict__ B1, const u16* __restrict__ B2,
    float* __restrict__ Cf, u16* __restrict__ C0, u16* __restrict__ C1,
    u16* __restrict__ C2) {
  extern __shared__ __align__(16) u16 smem[];
  // T1: bijective XCD swizzle over flattened grid (x fastest; gridDim=(4,64,z))
  const int nwg = (int)(gridDim.x * gridDim.y * gridDim.z);
  const int wg = (int)(blockIdx.x + (blockIdx.y << 2) + (blockIdx.z << 8));
  const int cpx = nwg >> 3;
  const int swz = (wg & 7) * cpx + (wg >> 3);
  const int bx = swz & 3;
  const int by = (swz >> 2) & 63;
  const int bz = swz >> 8;

  const u16* __restrict__ A;
  const u16* __restrict__ Bt;
  u16* __restrict__ Cb;
  if (TRIPLE) {
    switch (bz) {
      case 0: A = A0; Bt = B0; Cb = C0; break;
      case 1: A = A1; Bt = B1; Cb = C1; break;
      default: A = A2; Bt = B2; Cb = C2; break;
    }
  } else {
    A = A0; Bt = B0; Cb = C0;
  }

  const int tid = threadIdx.x;
  const int lane = tid & 63;
  const int wave = tid >> 6;        // 0..7
  const int wr = (wave >> 2) * 64;  // 0 / 64
  const int wc = (wave & 3) * 64;   // 0 / 64 / 128 / 192
  const int fr = lane & 15;
  const int fq = lane >> 4;
  const int s8 = fr & 7;            // == (frag row) & 7
  const int row0 = by * 128;
  const int col0 = bx * 256;

  // per-lane LDS frag offsets (u16 units), loop-invariant
  int aoff[4][2], boff[4][2];
#pragma unroll
  for (int mi = 0; mi < 4; mi++)
#pragma unroll
    for (int ks = 0; ks < 2; ks++)
      aoff[mi][ks] = (wr + mi * 16 + fr) * 64 + (((ks * 4 + fq) ^ s8) * 8);
#pragma unroll
  for (int nj = 0; nj < 4; nj++)
#pragma unroll
    for (int ks = 0; ks < 2; ks++)
      boff[nj][ks] = (wc + nj * 16 + fr) * 64 + (((ks * 4 + fq) ^ s8) * 8);

  // stage tile kt (6 x 16B per thread) into buffer q; global source is
  // pre-swizzled so linear LDS dest + swizzled read = consistent involution.
  auto stage = [&](int kt, int q) {
    const u16* __restrict__ gA = A + (size_t)row0 * 1024 + kt * 64;
    const u16* __restrict__ gB = Bt + (size_t)col0 * 1024 + kt * 64;
    u16* dA = smem + q * DP_SBUF;
    u16* dB = dA + DP_ABUF;
#pragma unroll
    for (int p = 0; p < 2; p++) {
      int pos = tid + p * 512;          // 0..1023
      int r = pos >> 3, gch = (pos & 7) ^ (r & 7);
      __builtin_amdgcn_global_load_lds(
          (const __attribute__((address_space(1))) void*)(gA + (size_t)r * 1024 + gch * 8),
          (__attribute__((address_space(3))) void*)(dA + pos * 8), 16, 0, 0);
    }
#pragma unroll
    for (int p = 0; p < 4; p++) {
      int pos = tid + p * 512;          // 0..2047
      int r = pos >> 3, gch = (pos & 7) ^ (r & 7);
      __builtin_amdgcn_global_load_lds(
          (const __attribute__((address_space(1))) void*)(gB + (size_t)r * 1024 + gch * 8),
          (__attribute__((address_space(3))) void*)(dB + pos * 8), 16, 0, 0);
    }
  };

  f32x4 acc[4][4];
#pragma unroll
  for (int mi = 0; mi < 4; mi++)
#pragma unroll
    for (int nj = 0; nj < 4; nj++) acc[mi][nj] = (f32x4){0.f, 0.f, 0.f, 0.f};

  auto iter_body = [&](int qc, int qs, bool dostage, int t2) {
    if (dostage) stage(t2, qs);  // issue next+1 tile loads early
    const u16* sA = smem + qc * DP_SBUF;
    const u16* sB = sA + DP_ABUF;
    bf16x8 av[4][2], bv[4][2];
#pragma unroll
    for (int mi = 0; mi < 4; mi++)
#pragma unroll
      for (int ks = 0; ks < 2; ks++)
        av[mi][ks] = *(const bf16x8*)(sA + aoff[mi][ks]);
#pragma unroll
    for (int nj = 0; nj < 4; nj++)
#pragma unroll
      for (int ks = 0; ks < 2; ks++)
        bv[nj][ks] = *(const bf16x8*)(sB + boff[nj][ks]);
    __builtin_amdgcn_s_setprio(1);
#pragma unroll
    for (int ks = 0; ks < 2; ks++)
#pragma unroll
      for (int mi = 0; mi < 4; mi++)
#pragma unroll
        for (int nj = 0; nj < 4; nj++)
          acc[mi][nj] = __builtin_amdgcn_mfma_f32_16x16x32_bf16(
              av[mi][ks], bv[nj][ks], acc[mi][nj], 0, 0, 0);
    __builtin_amdgcn_s_setprio(0);
  };

  // prologue: 2 tiles in flight (12 loads)
  stage(0, 0);
  stage(1, 1);
  int qc = 0, qs = 2;
  // main loop: wait current tile (vmcnt 6: leaves next tile's 6 in flight)
  for (int t = 0; t < 14; t++) {
    asm volatile("s_waitcnt vmcnt(6)" ::: "memory");
    __builtin_amdgcn_s_barrier();
    iter_body(qc, qs, true, t + 2);
    qc = (qc == 2) ? 0 : qc + 1;
    qs = (qs == 2) ? 0 : qs + 1;
  }
  // t = 14: no more staging; tile 15's 6 loads remain in flight
  asm volatile("s_waitcnt vmcnt(6)" ::: "memory");
  __builtin_amdgcn_s_barrier();
  iter_body(qc, 0, false, 0);
  qc = (qc == 2) ? 0 : qc + 1;
  // t = 15: drain
  asm volatile("s_waitcnt vmcnt(0)" ::: "memory");
  __builtin_amdgcn_s_barrier();
  iter_body(qc, 0, false, 0);

#pragma unroll
  for (int mi = 0; mi < 4; mi++) {
    int grow = row0 + wr + mi * 16 + fq * 4;
#pragma unroll
    for (int nj = 0; nj < 4; nj++) {
      int gcol = col0 + wc + nj * 16 + fr;
#pragma unroll
      for (int r = 0; r < 4; r++) {
        if (F32OUT)
          Cf[(size_t)(grow + r) * 1024 + gcol] = acc[mi][nj][r];
        else
          Cb[(size_t)(grow + r) * 1024 + gcol] = f2b(acc[mi][nj][r]);
      }
    }
  }
}

// ---------------------------------------------------------------------------
// 3. blend via MFMA (fused x/xx/tm* epilogue); xx recomputed inline from x.
// ---------------------------------------------------------------------------
__global__ __launch_bounds__(256) void blend_mfma(
    const u16* __restrict__ mb, const u16* __restrict__ w2T,
    const float* __restrict__ x,
    const float* __restrict__ tmw, const float* __restrict__ tmk,
    const float* __restrict__ tmv, const float* __restrict__ tmr,
    u16* __restrict__ xwb, u16* __restrict__ xkb, u16* __restrict__ xvb,
    u16* __restrict__ xrb) {
  __shared__ u16 mS[64 * 136];
  __shared__ u16 wS[64 * 136];
  const int tid = threadIdx.x;
  const int lane = tid & 63;
  const int w = tid >> 6;
  const int fr = lane & 15;
  const int fq = lane >> 4;
  const int c0 = blockIdx.x * 64;
  const int bt0 = blockIdx.y * 64;

#pragma unroll
  for (int it = 0; it < 4; it++) {
    int idx = tid + it * 256;  // 0..1023
    int r = idx >> 4, c8 = (idx & 15) * 8;
    bf16x8 v = *(const bf16x8*)(mb + (size_t)(bt0 + r) * 128 + c8);
    *(bf16x4*)(mS + r * 136 + c8) = __builtin_shufflevector(v, v, 0, 1, 2, 3);
    *(bf16x4*)(mS + r * 136 + c8 + 4) = __builtin_shufflevector(v, v, 4, 5, 6, 7);
    bf16x8 u = *(const bf16x8*)(w2T + (size_t)(c0 + r) * 128 + c8);
    *(bf16x4*)(wS + r * 136 + c8) = __builtin_shufflevector(u, u, 0, 1, 2, 3);
    *(bf16x4*)(wS + r * 136 + c8 + 4) = __builtin_shufflevector(u, u, 4, 5, 6, 7);
  }
  __syncthreads();

  f32x4 acc[4][4];  // [col-tile j][f]
#pragma unroll
  for (int j = 0; j < 4; j++)
#pragma unroll
    for (int f = 0; f < 4; f++) acc[j][f] = (f32x4){0.f, 0.f, 0.f, 0.f};

#pragma unroll
  for (int f = 0; f < 4; f++) {
    bf16x8 aA = ldfrag(mS + (w * 16 + fr) * 136 + f * 32 + fq * 8);
#pragma unroll
    for (int j = 0; j < 4; j++) {
      bf16x8 bB = ldfrag(wS + (j * 16 + fr) * 136 + f * 32 + fq * 8);
      acc[j][f] = __builtin_amdgcn_mfma_f32_16x16x32_bf16(aA, bB, acc[j][f], 0, 0, 0);
    }
  }

#pragma unroll
  for (int j = 0; j < 4; j++) {
    int c = c0 + j * 16 + fr;
    float w_ = tmw[c], k_ = tmk[c], v_ = tmv[c], r_ = tmr[c];
#pragma unroll
    for (int rr = 0; rr < 4; rr++) {
      int bt = bt0 + w * 16 + fq * 4 + rr;
      size_t g = (size_t)bt * 1024 + c;
      float xv_ = x[g];
      float xp = ((bt & 2047) != 0) ? x[g - 1024] : 0.f;
      float dx = xp - xv_;
      xwb[g] = f2b(xv_ + dx * (w_ + acc[j][0][rr]));
      xkb[g] = f2b(xv_ + dx * (k_ + acc[j][1][rr]));
      xvb[g] = f2b(xv_ + dx * (v_ + acc[j][2][rr]));
      xrb[g] = f2b(xv_ + dx * (r_ + acc[j][3][rr]));
    }
  }
}

// ---------------------------------------------------------------------------
// 5b. fused decay GEMM: h1 = tanh(xw @ d1) via MFMA (K=1024), then
//     wlog = -exp(tdr + h1 @ dw2r) via a second 2-step MFMA. 64-row tiles.
// ---------------------------------------------------------------------------
__global__ __launch_bounds__(256) void decay_mfma(const u16* __restrict__ xwb,
                                                  const u16* __restrict__ d1T,
                                                  const u16* __restrict__ dw2rbT,
                                                  const float* __restrict__ tdr,
                                                  float* __restrict__ wlog) {
  __shared__ u16 As[64 * 32];
  __shared__ u16 Bs[64 * 32];
  __shared__ u16 h1S[64 * 72];
  __shared__ u16 dwS[16 * 72];
  const int tid = threadIdx.x;
  const int lane = tid & 63;
  const int w = tid >> 6;
  const int fr = lane & 15;
  const int fq = lane >> 4;
  const int bt0 = blockIdx.x * 64;

#pragma unroll
  for (int it = 0; it < 4; it++) {
    int idx = tid + it * 256;
    int r = idx >> 6, c = idx & 63;
    dwS[r * 72 + c] = dw2rbT[r * 64 + c];
  }

  f32x4 acc[4];
#pragma unroll
  for (int j = 0; j < 4; j++) acc[j] = (f32x4){0.f, 0.f, 0.f, 0.f};

  const int ra = tid >> 2, ca = (tid & 3) * 8;
  for (int k0 = 0; k0 < 1024; k0 += 32) {
    __builtin_amdgcn_global_load_lds(
        (const __attribute__((address_space(1))) void*)(xwb + (size_t)(bt0 + ra) * 1024 + k0 + ca),
        (__attribute__((address_space(3))) void*)(As + tid * 8), 16, 0, 0);
    __builtin_amdgcn_global_load_lds(
        (const __attribute__((address_space(1))) void*)(d1T + (size_t)ra * 1024 + k0 + ca),
        (__attribute__((address_space(3))) void*)(Bs + tid * 8), 16, 0, 0);
    __syncthreads();
    bf16x8 aA = *(const bf16x8*)(As + ((w * 16 + fr) * 32 + fq * 8));
#pragma unroll
    for (int j = 0; j < 4; j++) {
      bf16x8 bB = *(const bf16x8*)(Bs + ((j * 16 + fr) * 32 + fq * 8));
      acc[j] = __builtin_amdgcn_mfma_f32_16x16x32_bf16(aA, bB, acc[j], 0, 0, 0);
    }
    __syncthreads();
  }
#pragma unroll
  for (int j = 0; j < 4; j++)
#pragma unroll
    for (int rr = 0; rr < 4; rr++)
      h1S[(w * 16 + fq * 4 + rr) * 72 + j * 16 + fr] = f2b(tanhf(acc[j][rr]));
  __syncthreads();

  f32x4 a2 = (f32x4){0.f, 0.f, 0.f, 0.f};
#pragma unroll
  for (int ks = 0; ks < 2; ks++) {
    bf16x8 aA = ldfrag(h1S + (w * 16 + fr) * 72 + ks * 32 + fq * 8);
    bf16x8 bB = ldfrag(dwS + fr * 72 + ks * 32 + fq * 8);
    a2 = __builtin_amdgcn_mfma_f32_16x16x32_bf16(aA, bB, a2, 0, 0, 0);
  }
  float tdv = tdr[fr];
#pragma unroll
  for (int rr = 0; rr < 4; rr++) {
    int bt = bt0 + w * 16 + fq * 4 + rr;
    int b = bt >> 11, tl = bt & 2047;
    wlog[((size_t)(b * 16 + fr)) * 2048 + tl] = -__expf(tdv + a2[rr]);
  }
}

// ---------------------------------------------------------------------------
// 7. per-chunk scan
// ---------------------------------------------------------------------------
__global__ __launch_bounds__(256) void wprep_kernel(const float* __restrict__ wlog,
                                                    float* __restrict__ cum,
                                                    float* __restrict__ excl,
                                                    float* __restrict__ wsl) {
  int bid = blockIdx.x;
  int c = bid & 7, bh = bid >> 3;
  int q = threadIdx.x;
  float v = wlog[(size_t)bh * 2048 + c * 256 + q];
  __shared__ float s[256];
  s[q] = v;
  float val = v;
  for (int off = 1; off < 256; off <<= 1) {
    __syncthreads();
    float t = (q >= off) ? s[q - off] : 0.f;
    __syncthreads();
    val += t;
    s[q] = val;
  }
  __syncthreads();
  float total = s[255];
  cum[(size_t)bid * 256 + q] = val;
  excl[(size_t)bid * 256 + q] = val - v;
  if (q == 0) wsl[bid] = total;
}

// ---------------------------------------------------------------------------
// kvfuse: per (bh, chunk) block — transpose k,v quarters into LDS, compute
// diag (full-wave reduce), write vT (global, for attn), and accumulate
// kv = (k*w_inter)^T @ v via MFMA in the same kernel. Eliminates the kTw
// global round-trip and kv_mfma's vT re-read entirely.
// grid 512 = bh*8 + c; 256 threads.
// ---------------------------------------------------------------------------
__global__ __launch_bounds__(256) void kvfuse_kernel(
    const u16* __restrict__ vb, const u16* __restrict__ kb,
    const u16* __restrict__ rb, const float* __restrict__ faaaa,
    const float* __restrict__ cum, const float* __restrict__ wsl,
    u16* __restrict__ vT, float* __restrict__ diagG, float* __restrict__ kvb) {
  int bid = blockIdx.x;
  int c = bid & 7, bh = bid >> 3;
  int b = bh >> 4, h = bh & 15;
  __shared__ float tv[64][65];
  __shared__ float tk[64][65];
  __shared__ u16 kSb[64 * 72];
  __shared__ u16 vSb[64 * 72];
  __shared__ float wfacS[256];
  __shared__ float faS[64];
  const int tid = threadIdx.x;
  const int lane = tid & 63;
  const int w = tid >> 6;
  const int fr = lane & 15;
  const int fq = lane >> 4;
  const int m = lane;

  float wslog = wsl[bid];
  wfacS[tid] = __expf(wslog - cum[(size_t)bid * 256 + tid]);
  if (tid < 64) faS[tid] = faaaa[h * 64 + tid];

  f32x4 acc[4];
#pragma unroll
  for (int j = 0; j < 4; j++) acc[j] = (f32x4){0.f, 0.f, 0.f, 0.f};

  for (int qt = 0; qt < 4; qt++) {
    __syncthreads();  // tv/tk free (prev transpose done); wfacS/faS ready
    float fam = faS[m];
    int t0 = c * QQ + qt * 64;
#pragma unroll
    for (int it = 0; it < 16; it++) {
      int r = it * 4 + w;
      size_t g = ((size_t)(b * TT + t0 + r)) * CC + h * 64 + m;
      float vraw = b2f(vb[g]);
      float kraw = b2f(kb[g]);
      float rraw = b2f(rb[g]);
      tv[r][m] = vraw;
      tk[r][m] = kraw;
      float s = rraw * fam * kraw;
      s += __shfl_xor(s, 1);
      s += __shfl_xor(s, 2);
      s += __shfl_xor(s, 4);
      s += __shfl_xor(s, 8);
      s += __shfl_xor(s, 16);
      s += __shfl_xor(s, 32);
      if (m == 0) diagG[(size_t)bh * 2048 + t0 + r] = s;
    }
    __syncthreads();
#pragma unroll
    for (int it = 0; it < 16; it++) {
      int idx = it * 256 + tid;
      int mm = idx >> 6, tl = idx & 63;
      float vv = tv[tl][mm];
      float kk = tk[tl][mm] * wfacS[qt * 64 + tl];
      u16 vbv = f2b(vv);
      vT[((size_t)(bh * 64 + mm)) * TT + t0 + tl] = vbv;
      vSb[mm * 72 + tl] = vbv;
      kSb[mm * 72 + tl] = f2b(kk);
    }
    __syncthreads();
#pragma unroll
    for (int ks = 0; ks < 2; ks++) {
      bf16x8 aA = ldfrag(kSb + (w * 16 + fr) * 72 + ks * 32 + fq * 8);
#pragma unroll
      for (int j = 0; j < 4; j++) {
        bf16x8 bB = ldfrag(vSb + (j * 16 + fr) * 72 + ks * 32 + fq * 8);
        acc[j] = __builtin_amdgcn_mfma_f32_16x16x32_bf16(aA, bB, acc[j], 0, 0, 0);
      }
    }
  }
#pragma unroll
  for (int j = 0; j < 4; j++)
#pragma unroll
    for (int rr = 0; rr < 4; rr++)
      kvb[(size_t)bid * 4096 + (w * 16 + fq * 4 + rr) * 64 + j * 16 + fr] = acc[j][rr];
}

// ---------------------------------------------------------------------------
// 8b. sequential state scan over chunks — 256 blocks (bh x 4 slices)
// ---------------------------------------------------------------------------
__global__ __launch_bounds__(256) void scan_kernel(const float* __restrict__ kvb,
                                                   const float* __restrict__ wsl,
                                                   float* __restrict__ st) {
  int bh = blockIdx.x >> 2;
  int sl = blockIdx.x & 3;
  int tid = threadIdx.x;
  float s[4];
#pragma unroll
  for (int i = 0; i < 4; i++) s[i] = 0.f;
  for (int c = 0; c < 8; c++) {
    int bid = bh * 8 + c;
    float w = __expf(wsl[bid]);
#pragma unroll
    for (int i = 0; i < 4; i++) {
      size_t e = (size_t)bid * 4096 + sl * 1024 + i * 256 + tid;
      st[e] = s[i];
      s[i] = w * s[i] + kvb[e];
    }
  }
}

// ---------------------------------------------------------------------------
// 9. MFMA fused attention. Mask via factored exp tables:
// exp(excl[q]-cum[k]) = exp(excl[q]-cc) * exp(cc-cum[k]), cc = cum[127]
// (both exponents bounded ~|47| -> no overflow; true product <= 1).
// Diagonal read from diagG (precomputed in kvfuse).
// ---------------------------------------------------------------------------
__global__ __launch_bounds__(256) void attn_mfma(
    const u16* __restrict__ rb, const u16* __restrict__ kb,
    const u16* __restrict__ vT, const float* __restrict__ stg,
    const float* __restrict__ cum, const float* __restrict__ excl,
    const float* __restrict__ diagG, float* __restrict__ y) {
  int bid = blockIdx.x;
  int c = bid & 7, bh = bid >> 3;
  int b = bh >> 4, h = bh & 15;
  __shared__ u16 rt[64 * 72];
  __shared__ u16 kt[64 * 72];
  __shared__ u16 vt[64 * 72];
  __shared__ u16 pt[64 * 72];
  __shared__ u16 stT[64 * 72];
  __shared__ float cumS[256], exS[256], diagS[256], ekS[256];

  const int tid = threadIdx.x;
  const int lane = tid & 63;
  const int w = tid >> 6;
  const int fr = lane & 15;
  const int fq = lane >> 4;

  cumS[tid] = cum[(size_t)bid * 256 + tid];
  exS[tid] = excl[(size_t)bid * 256 + tid];
  diagS[tid] = diagG[(size_t)bh * 2048 + c * 256 + tid];
#pragma unroll
  for (int it = 0; it < 16; it++) {
    int idx = tid + it * 256;
    int n = idx >> 6, mm = idx & 63;
    stT[mm * 72 + n] = f2b(stg[(size_t)bid * 4096 + idx]);
  }
  __syncthreads();
  const float ccm = cumS[127];
  ekS[tid] = __expf(ccm - cumS[tid]);

  const size_t rowbase = ((size_t)b * TT + c * QQ) * CC + h * 64;
  const size_t vbase0 = (size_t)bh * 64 * TT + c * QQ;

  for (int qt = 0; qt < 4; qt++) {
    __syncthreads();
    stage_tile(rb, rowbase + (size_t)(qt * 64) * CC, CC, tid, rt);
    __syncthreads();

    f32x4 acc[4];
#pragma unroll
    for (int jm = 0; jm < 4; jm++) acc[jm] = (f32x4){0.f, 0.f, 0.f, 0.f};
    bf16x8 rA[2];
    rA[0] = ldfrag(rt + (w * 16 + fr) * 72 + fq * 8);
    rA[1] = ldfrag(rt + (w * 16 + fr) * 72 + 32 + fq * 8);
#pragma unroll
    for (int ks = 0; ks < 2; ks++)
#pragma unroll
      for (int jm = 0; jm < 4; jm++) {
        bf16x8 bB = ldfrag(stT + (jm * 16 + fr) * 72 + ks * 32 + fq * 8);
        acc[jm] = __builtin_amdgcn_mfma_f32_16x16x32_bf16(rA[ks], bB, acc[jm], 0, 0, 0);
      }
    int ql0 = w * 16 + fq * 4;
    float er[4], eqc[4];
#pragma unroll
    for (int rr = 0; rr < 4; rr++) {
      float ex = exS[qt * 64 + ql0 + rr];
      er[rr] = __expf(ex);
      eqc[rr] = __expf(ex - ccm);
    }
#pragma unroll
    for (int jm = 0; jm < 4; jm++)
#pragma unroll
      for (int rr = 0; rr < 4; rr++) acc[jm][rr] *= er[rr];

    for (int kti = 0; kti <= qt; kti++) {
      __syncthreads();
      stage_tile(kb, rowbase + (size_t)(kti * 64) * CC, CC, tid, kt);
      stage_tile(vT, vbase0 + (size_t)(kti * 64), TT, tid, vt);
      __syncthreads();

      f32x4 sacc[4];
#pragma unroll
      for (int jj = 0; jj < 4; jj++) sacc[jj] = (f32x4){0.f, 0.f, 0.f, 0.f};
#pragma unroll
      for (int ks = 0; ks < 2; ks++)
#pragma unroll
        for (int jj = 0; jj < 4; jj++) {
          bf16x8 bB = ldfrag(kt + (jj * 16 + fr) * 72 + ks * 32 + fq * 8);
          sacc[jj] = __builtin_amdgcn_mfma_f32_16x16x32_bf16(rA[ks], bB, sacc[jj], 0, 0, 0);
        }
#pragma unroll
      for (int jj = 0; jj < 4; jj++) {
        int kcol = kti * 64 + jj * 16 + fr;
        float ek = ekS[kcol];
#pragma unroll
        for (int rr = 0; rr < 4; rr++) {
          int qrow = qt * 64 + ql0 + rr;
          float vsc;
          if (kcol < qrow)
            vsc = sacc[jj][rr] * eqc[rr] * ek;
          else if (kcol == qrow)
            vsc = diagS[qrow];
          else
            vsc = 0.f;
          pt[(ql0 + rr) * 72 + jj * 16 + fr] = f2b(vsc);
        }
      }
      __syncthreads();
#pragma unroll
      for (int ks = 0; ks < 2; ks++) {
        bf16x8 pA = ldfrag(pt + (w * 16 + fr) * 72 + ks * 32 + fq * 8);
#pragma unroll
        for (int jm = 0; jm < 4; jm++) {
          bf16x8 vB = ldfrag(vt + (jm * 16 + fr) * 72 + ks * 32 + fq * 8);
          acc[jm] = __builtin_amdgcn_mfma_f32_16x16x32_bf16(pA, vB, acc[jm], 0, 0, 0);
        }
      }
    }
    int qg0 = qt * 64 + w * 16 + fq * 4;
#pragma unroll
    for (int jm = 0; jm < 4; jm++)
#pragma unroll
      for (int rr = 0; rr < 4; rr++)
        y[rowbase + (size_t)(qg0 + rr) * CC + jm * 16 + fr] = acc[jm][rr];
  }
}

// ---------------------------------------------------------------------------
// 10. LayerNorm over C -> bf16
// ---------------------------------------------------------------------------
__global__ __launch_bounds__(256) void ln_kernel(const float* __restrict__ y,
                                                 const float* __restrict__ g,
                                                 const float* __restrict__ bta,
                                                 u16* __restrict__ out) {
  __shared__ float red[8];
  int bt = blockIdx.x;
  int tid = threadIdx.x;
  float v[4];
  float s = 0.f;
#pragma unroll
  for (int i = 0; i < 4; i++) {
    v[i] = y[(size_t)bt * 1024 + i * 256 + tid];
    s += v[i];
  }
#pragma unroll
  for (int off = 32; off > 0; off >>= 1) s += __shfl_down(s, off);
  if ((tid & 63) == 0) red[tid >> 6] = s;
  __syncthreads();
  if (tid == 0) red[4] = red[0] + red[1] + red[2] + red[3];
  __syncthreads();
  float mu = red[4] * (1.f / 1024.f);
  float s2 = 0.f;
#pragma unroll
  for (int i = 0; i < 4; i++) {
    float d = v[i] - mu;
    s2 += d * d;
  }
#pragma unroll
  for (int off = 32; off > 0; off >>= 1) s2 += __shfl_down(s2, off);
  __syncthreads();
  if ((tid & 63) == 0) red[tid >> 6] = s2;
  __syncthreads();
  if (tid == 0) red[5] = red[0] + red[1] + red[2] + red[3];
  __syncthreads();
  float var = red[5] * (1.f / 1024.f);
  float rstd = rsqrtf(var + 1e-5f);
#pragma unroll
  for (int i = 0; i < 4; i++) {
    int c = i * 256 + tid;
    out[(size_t)bt * 1024 + c] = f2b((v[i] - mu) * rstd * g[c] + bta[c]);
  }
}

// ---------------------------------------------------------------------------
extern "C" void kernel_launch(void* const* d_in, const int* in_sizes, int n_in,
                              void* d_out, int out_size, void* d_ws,
                              size_t ws_size, hipStream_t stream) {
  const float* x = (const float*)d_in[0];
  const float* tmx = (const float*)d_in[1];
  const float* tmw = (const float*)d_in[2];
  const float* tmk = (const float*)d_in[3];
  const float* tmv = (const float*)d_in[4];
  const float* tmr = (const float*)d_in[5];
  const float* maa_w1 = (const float*)d_in[6];
  const float* maa_w2 = (const float*)d_in[7];
  const float* decay_w1 = (const float*)d_in[8];
  const float* decay_w2 = (const float*)d_in[9];
  const float* time_decay = (const float*)d_in[10];
  const float* faaaa = (const float*)d_in[11];
  const float* Wr = (const float*)d_in[12];
  const float* Wk = (const float*)d_in[13];
  const float* Wv = (const float*)d_in[14];
  const float* Wo = (const float*)d_in[15];
  const float* lng = (const float*)d_in[16];
  const float* lnb = (const float*)d_in[17];
  float* out = (float*)d_out;
  float* ws = (float*)d_ws;

  const size_t S = (size_t)BT * CC;  // 8388608

  // f32 region
  float* y_ = ws;                     // attn out
  float* dw2r = ws + S;               // 1024
  float* tdr = dw2r + 1024;           // pad to 1024
  float* wlog = tdr + 1024;           // 131072
  float* cum = wlog + 131072;
  float* excl = cum + 131072;
  float* wsl = excl + 131072;         // pad to 1024
  float* diagG = wsl + 1024;          // 131072
  float* kvb = diagG + 131072;        // 512*4096
  float* stb = kvb + (size_t)512 * 4096;
  float* fend = stb + (size_t)512 * 4096;
  // bf16 region (u16)
  u16* xxxb = (u16*)fend;             // mix out -> maa GEMM in -> vT
  u16* mb = xxxb + S;                 // BT*128
  u16* xkb = mb + (size_t)BT * 128;   // blend out -> gemm_dp in -> ylnb
  u16* xvb = xkb + S;                 // blend out -> gemm_dp in
  u16* xrb = xvb + S;                 // blend out -> gemm_dp in
  u16* xwb = xrb + S;                 // blend out -> decay_mfma in
  u16* rb16 = xwb + S;                // gemm_dp out
  u16* kb16 = rb16 + S;               // gemm_dp out
  u16* Vb = kb16 + S;                 // gemm_dp out
  u16* Wrt = Vb + S;
  u16* Wkt = Wrt + (size_t)1024 * 1024;
  u16* Wvt = Wkt + (size_t)1024 * 1024;
  u16* Wot = Wvt + (size_t)1024 * 1024;
  u16* w1T = Wot + (size_t)1024 * 1024;   // [128][1024]
  u16* w2T = w1T + (size_t)128 * 1024;    // [1024][128]
  u16* d1T = w2T + (size_t)1024 * 128;    // [64][1024]
  u16* dw2rbT = d1T + (size_t)64 * 1024;  // [16][64]
  // aliases (stream-ordered reuse)
  u16* vT = xxxb;   // after maa GEMM consumed xxxb
  u16* ylnb = xkb;  // after gemm_dp consumed xkb

  // allow 144 KB dynamic LDS for the deep-pipelined GEMMs (once per process)
  static bool attr_done = false;
  if (!attr_done) {
    hipFuncSetAttribute((const void*)gemm_dp<true, false>,
                        hipFuncAttributeMaxDynamicSharedMemorySize, DP_SMEM_BYTES);
    hipFuncSetAttribute((const void*)gemm_dp<false, true>,
                        hipFuncAttributeMaxDynamicSharedMemorySize, DP_SMEM_BYTES);
    attr_done = true;
  }

  cvt_wT<<<dim3(16, 16, 4), 256, 0, stream>>>(Wr, Wk, Wv, Wo, Wrt, Wkt, Wvt, Wot);
  cvt3_T<<<dim3(16, 16, 4), 256, 0, stream>>>(maa_w1, maa_w2, decay_w1, w1T,
                                              w2T, d1T, decay_w2, time_decay,
                                              dw2r, tdr, dw2rbT);
  mix_kernel<<<8192, 256, 0, stream>>>(x, tmx, xxxb);
  gemm_maa<<<dim3(2, 128), 256, 0, stream>>>(xxxb, w1T, mb);
  blend_mfma<<<dim3(16, 128), 256, 0, stream>>>(mb, w2T, x, tmw, tmk, tmv, tmr,
                                                xwb, xkb, xvb, xrb);
  decay_mfma<<<128, 256, 0, stream>>>(xwb, d1T, dw2rbT, tdr, wlog);
  wprep_kernel<<<512, 256, 0, stream>>>(wlog, cum, excl, wsl);
  // fused r/k/v projections: deep-pipelined GEMM (R1 structure)
  gemm_dp<true, false><<<dim3(4, 64, 3), 512, DP_SMEM_BYTES, stream>>>(
      xrb, xkb, xvb, Wrt, Wkt, Wvt, nullptr, rb16, kb16, Vb);
  // fused transpose + diag + kv (replaces kvtrans2 + kv_mfma; kTw eliminated)
  kvfuse_kernel<<<512, 256, 0, stream>>>(Vb, kb16, rb16, faaaa, cum, wsl, vT,
                                         diagG, kvb);
  scan_kernel<<<256, 256, 0, stream>>>(kvb, wsl, stb);
  attn_mfma<<<512, 256, 0, stream>>>(rb16, kb16, vT, stb, cum, excl, diagG, y_);
  ln_kernel<<<BT, 256, 0, stream>>>(y_, lng, lnb, ylnb);
  // output projection: same deep-pipelined GEMM, f32 out
  gemm_dp<false, true><<<dim3(4, 64, 1), 512, DP_SMEM_BYTES, stream>>>(
      ylnb, nullptr, nullptr, Wot, nullptr, nullptr, out, nullptr, nullptr,
      nullptr);
}